// Round 4
// baseline (555.963 us; speedup 1.0000x reference)
//
#include <hip/hip_runtime.h>
#include <math.h>

// ---------------------------------------------------------------------------
// HDMOEM round 4: LDS-staged bf16 MFMA linear (fixes latency-bound W loads).
// B=4, C=4, H=W=64, E=4 experts/path, TOPK=2. Router masks all-True, ignored.
// ---------------------------------------------------------------------------

#define DEV_INLINE __device__ __forceinline__

typedef __attribute__((ext_vector_type(8))) short bf16x8;
typedef __attribute__((ext_vector_type(4))) float f32x4;

DEV_INLINE float mp_silu_f(float x) { return x / ((1.f + __expf(-x)) * 0.596f); }

DEV_INLINE unsigned short f2bf(float x) {
    unsigned u = __float_as_uint(x);
    unsigned r = (u + 0x7fffu + ((u >> 16) & 1u)) >> 16;
    return (unsigned short)r;
}
DEV_INLINE float bf2f(unsigned short u) { return __uint_as_float(((unsigned)u) << 16); }

// ---------------------------------------------------------------------------
struct RsEnt { const float* w; float* o; int fan; int rowStart; };
struct RsTab { RsEnt e[23]; };

__global__ void rowscale_all_kernel(RsTab t) {
    int r = blockIdx.x;
    int ti = 0;
#pragma unroll
    for (int j = 1; j < 23; ++j)
        if (r >= t.e[j].rowStart) ti = j;
    const float* p = t.e[ti].w;
    int fan = t.e[ti].fan;
    int row = r - t.e[ti].rowStart;
    p += (size_t)row * fan;
    float s = 0.f;
    for (int i = threadIdx.x; i < fan; i += 256) { float v = p[i]; s += v * v; }
    __shared__ float red[256];
    red[threadIdx.x] = s;
    __syncthreads();
    for (int st = 128; st > 0; st >>= 1) {
        if (threadIdx.x < st) red[threadIdx.x] += red[threadIdx.x + st];
        __syncthreads();
    }
    if (threadIdx.x == 0) {
        float mean = red[0] / (float)fan;
        t.e[ti].o[row] = 1.f / sqrtf((mean + 1e-8f) * (float)fan);
    }
}

// ---- mid-conv weights: [e][oc][ic][3][3] f32 -> [e][tap][oc][ic] bf16
__global__ void wmid_cvt_kernel(const float* __restrict__ w, unsigned short* __restrict__ wt) {
    int i = blockIdx.x * 256 + threadIdx.x;
    if (i >= 4 * 9 * 192 * 192) return;
    int ic = i % 192;
    int t = i / 192;
    int oc = t % 192; t /= 192;
    int tap = t % 9;
    int e = t / 9;
    wt[i] = f2bf(w[(((size_t)(e * 192 + oc) * 192 + ic) * 9) + tap]);
}

__global__ void femb_kernel(const float* __restrict__ tv, const float* __restrict__ fr,
                            const float* __restrict__ ph, float* __restrict__ femb) {
    int i = blockIdx.x * 256 + threadIdx.x;
    if (i >= 1024) return;
    int b = i >> 8, j = i & 255;
    femb[i] = 1.41421356237f * cosf(6.28318530717958647f * (tv[b] * fr[j] + ph[j]));
}

// ---- wave-per-output GEMV for small-M linears
template <int ACT, int HASRES>
__global__ void gemv_kernel(const float* __restrict__ A, const float* __restrict__ W,
                            const float* __restrict__ wsc, const float* __restrict__ res,
                            float osc, float* __restrict__ out, int N, int K) {
    int o = blockIdx.x * 4 + (threadIdx.x >> 6);
    int lane = threadIdx.x & 63;
    int m = o / N, n = o % N;
    const float* a = A + (size_t)m * K;
    const float* w = W + (size_t)n * K;
    float s = 0.f;
    for (int k = lane; k < K; k += 64) s += a[k] * w[k];
#pragma unroll
    for (int sh = 32; sh > 0; sh >>= 1) s += __shfl_xor(s, sh);
    if (lane == 0) {
        float val = s * wsc[n];
        if (ACT) val = mp_silu_f(val);
        if (HASRES) val = (val + res[(size_t)m * N + n]) * osc;
        out[(size_t)m * N + n] = val;
    }
}

__global__ void scale_kernel(const float* __restrict__ temb, const float* __restrict__ w,
                             const float* __restrict__ wsc, const float* __restrict__ zeta,
                             float* __restrict__ scale2) {
    __shared__ float lg[8];
    int t = threadIdx.x;
    if (t < 8) {
        int b = t >> 1, o = t & 1;
        float s = 0.f;
        for (int k = 0; k < 512; ++k) s += temb[b * 512 + k] * w[o * 512 + k];
        lg[t] = s * wsc[o] / zeta[0];
    }
    __syncthreads();
    if (t < 4) {
        float a = lg[t * 2], b2 = lg[t * 2 + 1];
        float m = fmaxf(a, b2);
        float e0 = expf(a - m), e1 = expf(b2 - m);
        float inv = 2.f / (e0 + e1);
        scale2[t * 2] = e0 * inv;
        scale2[t * 2 + 1] = e1 * inv;
    }
}

__global__ void meanx_kernel(const float* __restrict__ x, float* __restrict__ mean_x) {
    int bc = blockIdx.x;
    float s = 0.f;
    for (int i = threadIdx.x; i < 4096; i += 256) s += x[bc * 4096 + i];
    __shared__ float red[256];
    red[threadIdx.x] = s;
    __syncthreads();
    for (int st = 128; st > 0; st >>= 1) {
        if (threadIdx.x < st) red[threadIdx.x] += red[threadIdx.x + st];
        __syncthreads();
    }
    if (threadIdx.x == 0) mean_x[bc] = red[0] * (1.f / 4096.f);
}

// ---- routers: probs + top2; unet side also emits slot tables (eidx, gain)
__global__ void router_kernel(const float* __restrict__ mean_x, const float* __restrict__ scale2,
                              const float* __restrict__ temb,
                              const float* __restrict__ wu, const float* __restrict__ su,
                              const float* __restrict__ wv, const float* __restrict__ sv,
                              const float* __restrict__ zeta,
                              int* __restrict__ eidx, float* __restrict__ gain,
                              float* __restrict__ rwv,
                              float* __restrict__ probs_out) {
    __shared__ float lg[2][4][4];
    int t = threadIdx.x;
    if (t < 32) {
        int r = t >> 4, b = (t >> 2) & 3, e = t & 3;
        const float* w = (r == 0) ? wu : wv;
        const float* sc = (r == 0) ? su : sv;
        float ps = scale2[b * 2 + (r == 0 ? 1 : 0)];
        float acc = 0.f;
        for (int c = 0; c < 4; ++c) acc += mean_x[b * 4 + c] * ps * w[e * 516 + c];
        for (int j = 0; j < 512; ++j) acc += temb[b * 512 + j] * w[e * 516 + 4 + j];
        lg[r][b][e] = acc * sc[e] / zeta[0];
    }
    __syncthreads();
    if (t < 8) {
        int r = t >> 2, b = t & 3;
        float p[4];
        float mx = -1e30f;
        for (int e = 0; e < 4; ++e) mx = fmaxf(mx, lg[r][b][e]);
        float sum = 0.f;
        for (int e = 0; e < 4; ++e) { p[e] = expf(lg[r][b][e] - mx); sum += p[e]; }
        for (int e = 0; e < 4; ++e) p[e] /= sum;
        int i1 = 0;
        for (int e = 1; e < 4; ++e) if (p[e] > p[i1]) i1 = e;
        int i2 = -1;
        for (int e = 0; e < 4; ++e) { if (e == i1) continue; if (i2 < 0 || p[e] > p[i2]) i2 = e; }
        float inv = 1.f / (p[i1] + p[i2]);
        if (r == 0) {
            eidx[b * 2] = i1; eidx[b * 2 + 1] = i2;
            gain[b * 2] = p[i1] * inv; gain[b * 2 + 1] = p[i2] * inv;
        } else {
            for (int e = 0; e < 4; ++e) rwv[b * 4 + e] = 0.f;
            rwv[b * 4 + i1] = p[i1] * inv;
            rwv[b * 4 + i2] = p[i2] * inv;
        }
        for (int e = 0; e < 4; ++e) probs_out[r * 16 + b * 4 + e] = p[e];
    }
}

__global__ void make_inputs_kernel(const float* __restrict__ x, const float* __restrict__ scale2,
                                   float* __restrict__ in_vit, float* __restrict__ in_unet) {
    int i = blockIdx.x * 256 + threadIdx.x;
    if (i >= 65536) return;
    int b = i >> 14;
    float v = x[i];
    in_vit[i] = scale2[b * 2] * v;
    in_unet[i] = scale2[b * 2 + 1] * v;
}

__global__ void textp_kernel(const float* __restrict__ te, float* __restrict__ tp) {
    int i = blockIdx.x * 256 + threadIdx.x;
    if (i >= 3072) return;
    int b = i / 768, f = i % 768;
    float s = 0.f;
    for (int t = 0; t < 77; ++t) s += te[(size_t)(b * 77 + t) * 768 + f];
    tp[i] = s * (1.f / 77.f);
}

__global__ void patchify_kernel(const float* __restrict__ in_vit, float* __restrict__ pt) {
    int i = blockIdx.x * 256 + threadIdx.x;
    if (i >= 65536) return;
    int b = i >> 14;
    int r = i & 16383;
    int s = r >> 8, f = r & 255;
    int c = f >> 6, py = (f >> 3) & 7, px = f & 7;
    int gy = s >> 3, gx = s & 7;
    pt[i] = in_vit[((b * 4 + c) * 64 + gy * 8 + py) * 64 + gx * 8 + px];
}

// ---------------------------------------------------------------------------
// conv_in (slots): NCHW f32 -> NHWC bf16 per slot. grid (16,24,8)
__global__ void conv_in_kernel(const float* __restrict__ in, const float* __restrict__ wbase,
                               const float* __restrict__ wscb, const float* __restrict__ tvec,
                               const int* __restrict__ eidx,
                               unsigned short* __restrict__ out) {
    int z = blockIdx.z, b = z >> 1;
    int e = eidx[z];
    const float* w = wbase + (size_t)e * 6912;
    const float* wsc = wscb + e * 192;
    const float* tmod = tvec + b * 768 + e * 192;
    int tileIdx = blockIdx.x;
    int ty0 = (tileIdx >> 2) * 16, tx0 = (tileIdx & 3) * 16;
    int oc0 = blockIdx.y * 8;
    int lty = threadIdx.x >> 4, ltx = threadIdx.x & 15;
    int y = ty0 + lty, x = tx0 + ltx;
    __shared__ float tile[4][18][18];
    for (int i = threadIdx.x; i < 4 * 18 * 18; i += 256) {
        int ic = i / 324, rr = (i / 18) % 18, cc = i % 18;
        int gy = ty0 - 1 + rr, gx = tx0 - 1 + cc;
        float v = 0.f;
        if (gy >= 0 && gy < 64 && gx >= 0 && gx < 64)
            v = in[((b * 4 + ic) * 64 + gy) * 64 + gx];
        tile[ic][rr][cc] = v;
    }
    __syncthreads();
    float win[4][9];
#pragma unroll
    for (int ic = 0; ic < 4; ++ic)
#pragma unroll
        for (int ky = 0; ky < 3; ++ky)
#pragma unroll
            for (int kx = 0; kx < 3; ++kx)
                win[ic][ky * 3 + kx] = tile[ic][lty + ky][ltx + kx];
#pragma unroll
    for (int o = 0; o < 8; ++o) {
        int oc = oc0 + o;
        float acc = 0.f;
#pragma unroll
        for (int ic = 0; ic < 4; ++ic) {
            const float* wp = w + (size_t)(oc * 4 + ic) * 9;
#pragma unroll
            for (int kk = 0; kk < 9; ++kk) acc += wp[kk] * win[ic][kk];
        }
        float val = acc * wsc[oc] * (1.f + tmod[oc]);
        val = mp_silu_f(val);
        out[((z * 64 + y) * 64 + x) * 192 + oc] = f2bf(val);
    }
}

// ---------------------------------------------------------------------------
// mid conv (slots): implicit-GEMM bf16 MFMA. grid (32,3,8)
__global__ __launch_bounds__(256) void conv_mid_mfma(
    const unsigned short* __restrict__ in, const unsigned short* __restrict__ wtbase,
    const float* __restrict__ wscb, const int* __restrict__ eidx,
    unsigned short* __restrict__ out) {
    int z = blockIdx.z;
    int e = eidx[z];
    const unsigned short* wt = wtbase + (size_t)e * 331776;
    const float* wsc = wscb + e * 192;
    int y0 = blockIdx.x * 2;
    int oc0 = blockIdx.y * 64;
    int wid = threadIdx.x >> 6, lane = threadIdx.x & 63;
    int wm = wid >> 1, wn = wid & 1;
    int l15 = lane & 15, lq = lane >> 4;

    __shared__ unsigned short Alds[4 * 66 * 40];
    f32x4 acc[4][2];
#pragma unroll
    for (int g = 0; g < 4; ++g)
#pragma unroll
        for (int f = 0; f < 2; ++f) acc[g][f] = (f32x4){0.f, 0.f, 0.f, 0.f};

    for (int icc = 0; icc < 6; ++icc) {
        int ic0 = icc * 32;
        for (int i = threadIdx.x; i < 1056; i += 256) {
            int q = i & 3;
            int xx = (i >> 2) % 66;
            int r = (i >> 2) / 66;
            int y = y0 - 1 + r, xg = xx - 1;
            uint4 val = {0u, 0u, 0u, 0u};
            if (y >= 0 && y < 64 && xg >= 0 && xg < 64)
                val = *(const uint4*)&in[((z * 64 + y) * 64 + xg) * 192 + ic0 + q * 8];
            *(uint4*)&Alds[(r * 66 + xx) * 40 + q * 8] = val;
        }
        __syncthreads();
#pragma unroll
        for (int tap = 0; tap < 9; ++tap) {
            int ky = tap / 3, kx = tap % 3;
            bf16x8 bfr[2];
#pragma unroll
            for (int fn = 0; fn < 2; ++fn) {
                int oc = oc0 + wn * 32 + fn * 16 + l15;
                bfr[fn] = *(const bf16x8*)&wt[(size_t)(tap * 192 + oc) * 192 + ic0 + 8 * lq];
            }
            int r = wm + ky;
#pragma unroll
            for (int g = 0; g < 4; ++g) {
                int xx = g * 16 + l15 + kx;
                bf16x8 afr = *(const bf16x8*)&Alds[(r * 66 + xx) * 40 + 8 * lq];
                acc[g][0] = __builtin_amdgcn_mfma_f32_16x16x32_bf16(afr, bfr[0], acc[g][0], 0, 0, 0);
                acc[g][1] = __builtin_amdgcn_mfma_f32_16x16x32_bf16(afr, bfr[1], acc[g][1], 0, 0, 0);
            }
        }
        __syncthreads();
    }
    int orow = y0 + wm;
#pragma unroll
    for (int g = 0; g < 4; ++g)
#pragma unroll
        for (int fn = 0; fn < 2; ++fn) {
            int oc = oc0 + wn * 32 + fn * 16 + l15;
            float ws = wsc[oc];
#pragma unroll
            for (int r2 = 0; r2 < 4; ++r2) {
                int px = g * 16 + lq * 4 + r2;
                float v = acc[g][fn][r2] * ws;
                v = mp_silu_f(v);
                out[((z * 64 + orow) * 64 + px) * 192 + oc] = f2bf(v);
            }
        }
}

// ---------------------------------------------------------------------------
// conv_out (slots, split-K): grid (16 tiles, 8 kchunks, 8 slots), atomicAdd.
__global__ __launch_bounds__(256) void conv_out_kernel(
    const unsigned short* __restrict__ in, const float* __restrict__ wbase,
    const float* __restrict__ wscb, const int* __restrict__ eidx,
    const float* __restrict__ gain, float* __restrict__ out) {
    int z = blockIdx.z, b = z >> 1;
    int e = eidx[z];
    float g = gain[z];
    const float* w = wbase + (size_t)e * 6912;
    const float* wsc = wscb + e * 4;
    int c0 = blockIdx.y * 24;
    int tileIdx = blockIdx.x;
    int ty0 = (tileIdx >> 2) * 16, tx0 = (tileIdx & 3) * 16;
    int lty = threadIdx.x >> 4, ltx = threadIdx.x & 15;
    int y = ty0 + lty, x = tx0 + ltx;
    __shared__ float tile[24][18][18];
    for (int i = threadIdx.x; i < 972; i += 256) {
        int q = i % 3, cell = i / 3;
        int rr = cell / 18, cc = cell % 18;
        int gy = ty0 - 1 + rr, gx = tx0 - 1 + cc;
        uint4 raw = {0u, 0u, 0u, 0u};
        if (gy >= 0 && gy < 64 && gx >= 0 && gx < 64)
            raw = *(const uint4*)&in[((z * 64 + gy) * 64 + gx) * 192 + c0 + q * 8];
        int icb = q * 8;
        tile[icb + 0][rr][cc] = bf2f((unsigned short)(raw.x & 0xffff));
        tile[icb + 1][rr][cc] = bf2f((unsigned short)(raw.x >> 16));
        tile[icb + 2][rr][cc] = bf2f((unsigned short)(raw.y & 0xffff));
        tile[icb + 3][rr][cc] = bf2f((unsigned short)(raw.y >> 16));
        tile[icb + 4][rr][cc] = bf2f((unsigned short)(raw.z & 0xffff));
        tile[icb + 5][rr][cc] = bf2f((unsigned short)(raw.z >> 16));
        tile[icb + 6][rr][cc] = bf2f((unsigned short)(raw.w & 0xffff));
        tile[icb + 7][rr][cc] = bf2f((unsigned short)(raw.w >> 16));
    }
    __syncthreads();
    float acc[4] = {0.f, 0.f, 0.f, 0.f};
#pragma unroll
    for (int ic = 0; ic < 24; ++ic) {
        float win[9];
#pragma unroll
        for (int ky = 0; ky < 3; ++ky)
#pragma unroll
            for (int kx = 0; kx < 3; ++kx)
                win[ky * 3 + kx] = tile[ic][lty + ky][ltx + kx];
#pragma unroll
        for (int o = 0; o < 4; ++o) {
            const float* wp = w + (size_t)(o * 192 + c0 + ic) * 9;
#pragma unroll
            for (int kk = 0; kk < 9; ++kk) acc[o] += wp[kk] * win[kk];
        }
    }
#pragma unroll
    for (int o = 0; o < 4; ++o)
        atomicAdd(&out[((b * 4 + o) * 64 + y) * 64 + x], g * acc[o] * wsc[o]);
}

// ---------------------------------------------------------------------------
// bf16 MFMA linear v2: BOTH A and W staged to LDS (f32->bf16 on stage).
// BM=64 (one batch), BN=64, 4 waves 2x2, each wave 32x32. grid (N/64, M/64, E).
template <int ACT>
__global__ __launch_bounds__(256) void mfma_linear_kernel(
    const float* __restrict__ A, int aE,
    const float* __restrict__ W, int wE,
    const float* __restrict__ wsc, int wscE,
    const float* __restrict__ pos, int posE,
    const float* __restrict__ cond, int condRow, int condE,
    const float* __restrict__ res, int resE, float outscale,
    const float* __restrict__ gate,
    float* __restrict__ out, int outE,
    int M, int N, int K) {
    int e = blockIdx.z;
    int bm = blockIdx.y * 64, bn = blockIdx.x * 64;
    if (gate && gate[(bm >> 6) * 4 + e] == 0.f) return;
    A += (size_t)e * aE;
    W += (size_t)e * wE;
    wsc += (size_t)e * wscE;
    if (pos) pos += (size_t)e * posE;
    if (cond) cond += (size_t)e * condE;
    if (res) res += (size_t)e * resE;
    out += (size_t)e * outE;

    int wid = threadIdx.x >> 6, lane = threadIdx.x & 63;
    int wm = wid >> 1, wn = wid & 1;
    int l15 = lane & 15, lq = lane >> 4;
    __shared__ unsigned short Al[64 * 72];
    __shared__ unsigned short Wl[64 * 72];
    f32x4 acc[2][2];
#pragma unroll
    for (int mf = 0; mf < 2; ++mf)
#pragma unroll
        for (int nf = 0; nf < 2; ++nf) acc[mf][nf] = (f32x4){0.f, 0.f, 0.f, 0.f};

    for (int k0 = 0; k0 < K; k0 += 64) {
#pragma unroll
        for (int p = 0; p < 4; ++p) {
            int i = threadIdx.x + p * 256;          // 0..1023
            int row = i >> 4, kq = (i & 15) * 4;
            float4 va = *(const float4*)&A[(size_t)(bm + row) * K + k0 + kq];
            float4 vw = *(const float4*)&W[(size_t)(bn + row) * K + k0 + kq];
            ushort4 sa, sw;
            sa.x = f2bf(va.x); sa.y = f2bf(va.y); sa.z = f2bf(va.z); sa.w = f2bf(va.w);
            sw.x = f2bf(vw.x); sw.y = f2bf(vw.y); sw.z = f2bf(vw.z); sw.w = f2bf(vw.w);
            *(ushort4*)&Al[row * 72 + kq] = sa;
            *(ushort4*)&Wl[row * 72 + kq] = sw;
        }
        __syncthreads();
#pragma unroll
        for (int ks = 0; ks < 2; ++ks) {
            bf16x8 af[2], wf[2];
#pragma unroll
            for (int mf = 0; mf < 2; ++mf)
                af[mf] = *(const bf16x8*)&Al[(wm * 32 + mf * 16 + l15) * 72 + ks * 32 + lq * 8];
#pragma unroll
            for (int nf = 0; nf < 2; ++nf)
                wf[nf] = *(const bf16x8*)&Wl[(wn * 32 + nf * 16 + l15) * 72 + ks * 32 + lq * 8];
#pragma unroll
            for (int mf = 0; mf < 2; ++mf)
#pragma unroll
                for (int nf = 0; nf < 2; ++nf)
                    acc[mf][nf] = __builtin_amdgcn_mfma_f32_16x16x32_bf16(af[mf], wf[nf], acc[mf][nf], 0, 0, 0);
        }
        __syncthreads();
    }
#pragma unroll
    for (int mf = 0; mf < 2; ++mf)
#pragma unroll
        for (int nf = 0; nf < 2; ++nf) {
            int n = bn + wn * 32 + nf * 16 + l15;
            float ws = wsc[n];
#pragma unroll
            for (int r = 0; r < 4; ++r) {
                int m = bm + wm * 32 + mf * 16 + lq * 4 + r;
                float val = acc[mf][nf][r] * ws;
                if (pos) val += pos[(m & 63) * N + n];
                if (cond) val *= (1.f + cond[(m >> 6) * condRow + n]);
                if (ACT) val = mp_silu_f(val);
                if (res) val = (val + res[(size_t)m * N + n]) * outscale;
                out[(size_t)m * N + n] = val;
            }
        }
}

// ---- ViT self-attention over (e,b,h); float4 LDS reads
__global__ void vit_attn_kernel(const float* __restrict__ qkv_base,
                                const float* __restrict__ rwv,
                                float* __restrict__ out_base) {
    int e = blockIdx.x >> 5, b = (blockIdx.x >> 3) & 3, h = blockIdx.x & 7;
    if (rwv[b * 4 + e] == 0.f) return;
    const float* qkv = qkv_base + (size_t)e * 393216;
    float* out = out_base + (size_t)e * 131072;
    __shared__ float ks[64][68], vs[64][68], sc[64][65];
    int tid = threadIdx.x;
    for (int i = tid; i < 4096; i += 64) {
        int j = i >> 6, d = i & 63;
        ks[j][d] = qkv[(size_t)(b * 64 + j) * 1536 + 512 + h * 64 + d];
        vs[j][d] = qkv[(size_t)(b * 64 + j) * 1536 + 1024 + h * 64 + d];
    }
    float qreg[64];
#pragma unroll
    for (int d = 0; d < 64; ++d) qreg[d] = qkv[(size_t)(b * 64 + tid) * 1536 + h * 64 + d];
    __syncthreads();
    float mx = -1e30f;
    for (int j = 0; j < 64; ++j) {
        float s = 0.f;
#pragma unroll
        for (int d4 = 0; d4 < 16; ++d4) {
            float4 kk = *(const float4*)&ks[j][d4 * 4];
            s += qreg[d4 * 4] * kk.x + qreg[d4 * 4 + 1] * kk.y +
                 qreg[d4 * 4 + 2] * kk.z + qreg[d4 * 4 + 3] * kk.w;
        }
        s *= 0.125f;
        sc[tid][j] = s;
        mx = fmaxf(mx, s);
    }
    float sum = 0.f;
    for (int j = 0; j < 64; ++j) { float ee = __expf(sc[tid][j] - mx); sc[tid][j] = ee; sum += ee; }
    float inv = 1.f / sum;
    float4 acc4[16];
#pragma unroll
    for (int d4 = 0; d4 < 16; ++d4) acc4[d4] = (float4){0.f, 0.f, 0.f, 0.f};
    for (int j = 0; j < 64; ++j) {
        float ee = sc[tid][j];
#pragma unroll
        for (int d4 = 0; d4 < 16; ++d4) {
            float4 vv = *(const float4*)&vs[j][d4 * 4];
            acc4[d4].x += ee * vv.x; acc4[d4].y += ee * vv.y;
            acc4[d4].z += ee * vv.z; acc4[d4].w += ee * vv.w;
        }
    }
    float* op = &out[(size_t)(b * 64 + tid) * 512 + h * 64];
#pragma unroll
    for (int d4 = 0; d4 < 16; ++d4) {
        float4 r;
        r.x = acc4[d4].x * inv; r.y = acc4[d4].y * inv;
        r.z = acc4[d4].z * inv; r.w = acc4[d4].w * inv;
        *(float4*)&op[d4 * 4] = r;
    }
}

__global__ void unpatch_scatter_kernel(const float* __restrict__ vout,
                                       const float* __restrict__ rwv,
                                       float* __restrict__ out_vit) {
    int i = blockIdx.x * 256 + threadIdx.x;
    if (i >= 65536) return;
    int b = i >> 14;
    int c = (i >> 12) & 3, y = (i >> 6) & 63, x = i & 63;
    int f = c * 64 + (y & 7) * 8 + (x & 7);
    int s = (y >> 3) * 8 + (x >> 3);
    int idx = (b * 64 + s) * 256 + f;
    float acc = 0.f;
#pragma unroll
    for (int e = 0; e < 4; ++e) {
        float g = rwv[b * 4 + e];
        if (g != 0.f) acc += g * vout[e * 65536 + idx];
    }
    out_vit[i] = acc;
}

__global__ void ca_qkv_kernel(const float* __restrict__ ou, const float* __restrict__ ov,
                              const float* __restrict__ wq, const float* __restrict__ sq,
                              const float* __restrict__ wk, const float* __restrict__ sk,
                              const float* __restrict__ wv, const float* __restrict__ sv,
                              float* __restrict__ q, float* __restrict__ kx, float* __restrict__ vx) {
    int i = blockIdx.x * 256 + threadIdx.x;
    if (i >= 16384) return;
    int b = i >> 12, t = i & 4095;
    float u[4], c[4];
#pragma unroll
    for (int cc = 0; cc < 4; ++cc) {
        u[cc] = ou[(size_t)(b * 4 + cc) * 4096 + t];
        c[cc] = ov[(size_t)(b * 4 + cc) * 4096 + t];
    }
#pragma unroll
    for (int o = 0; o < 4; ++o) {
        float aq = 0.f, ak = 0.f, av = 0.f;
#pragma unroll
        for (int cc = 0; cc < 4; ++cc) {
            aq += wq[o * 4 + cc] * u[cc];
            ak += wk[o * 4 + cc] * c[cc];
            av += wv[o * 4 + cc] * c[cc];
        }
        q[(size_t)(b * 4096 + t) * 4 + o] = aq * sq[o];
        kx[(size_t)(b * 4096 + t) * 4 + o] = ak * sk[o];
        vx[(size_t)(b * 4096 + t) * 4 + o] = av * sv[o];
    }
}

// ---- cross-attn: 8 key-segments x 8-key ILP batches, LDS merge
__global__ __launch_bounds__(512) void ca_attn_kernel(
    const float* __restrict__ q, const float* __restrict__ k,
    const float* __restrict__ v, float* __restrict__ o) {
    int b = blockIdx.x >> 6;
    int lq = threadIdx.x & 63, seg = threadIdx.x >> 6;
    int qt = ((blockIdx.x & 63) << 6) + lq;
    float4 qv = *(const float4*)&q[(size_t)(b * 4096 + qt) * 4];
    const float4* kb = (const float4*)(k + (size_t)b * 16384);
    const float4* vb = (const float4*)(v + (size_t)b * 16384);
    float m = -1e30f, l = 0.f, a0 = 0.f, a1 = 0.f, a2 = 0.f, a3 = 0.f;
    int j0 = seg * 512;
    for (int j = j0; j < j0 + 512; j += 8) {
        float s[8];
#pragma unroll
        for (int u = 0; u < 8; ++u) {
            float4 kk = kb[j + u];
            s[u] = 0.5f * (qv.x * kk.x + qv.y * kk.y + qv.z * kk.z + qv.w * kk.w);
        }
        float bm = fmaxf(fmaxf(fmaxf(s[0], s[1]), fmaxf(s[2], s[3])),
                         fmaxf(fmaxf(s[4], s[5]), fmaxf(s[6], s[7])));
        float nm = fmaxf(m, bm);
        float corr = __expf(m - nm);
        l *= corr; a0 *= corr; a1 *= corr; a2 *= corr; a3 *= corr;
#pragma unroll
        for (int u = 0; u < 8; ++u) {
            float ee = __expf(s[u] - nm);
            float4 vv = vb[j + u];
            l += ee;
            a0 += ee * vv.x; a1 += ee * vv.y; a2 += ee * vv.z; a3 += ee * vv.w;
        }
        m = nm;
    }
    __shared__ float red[8][64][8];
    red[seg][lq][0] = m; red[seg][lq][1] = l;
    red[seg][lq][2] = a0; red[seg][lq][3] = a1;
    red[seg][lq][4] = a2; red[seg][lq][5] = a3;
    __syncthreads();
    if (seg == 0) {
#pragma unroll
        for (int s2 = 1; s2 < 8; ++s2) {
            float m2 = red[s2][lq][0], l2 = red[s2][lq][1];
            float nm = fmaxf(m, m2);
            float c1 = __expf(m - nm), c2 = __expf(m2 - nm);
            l = l * c1 + l2 * c2;
            a0 = a0 * c1 + red[s2][lq][2] * c2;
            a1 = a1 * c1 + red[s2][lq][3] * c2;
            a2 = a2 * c1 + red[s2][lq][4] * c2;
            a3 = a3 * c1 + red[s2][lq][5] * c2;
            m = nm;
        }
        float inv = 1.f / l;
        float* op = &o[(size_t)(b * 4096 + qt) * 4];
        op[0] = a0 * inv; op[1] = a1 * inv; op[2] = a2 * inv; op[3] = a3 * inv;
    }
}

// ---- fused: out-proj + balanced blend + gated combine -> d_out
__global__ void ca_final_kernel(const float* __restrict__ ao, const float* __restrict__ ou,
                                const float* __restrict__ wo, const float* __restrict__ so,
                                const float* __restrict__ gw1, const float* __restrict__ s1,
                                const float* __restrict__ gw2, const float* __restrict__ s2,
                                float* __restrict__ out) {
    int i = blockIdx.x * 256 + threadIdx.x;
    if (i >= 16384) return;
    int b = i >> 12, t = i & 4095;
    float oo[4], u[4], a[4];
#pragma unroll
    for (int j = 0; j < 4; ++j) oo[j] = ao[(size_t)(b * 4096 + t) * 4 + j];
#pragma unroll
    for (int c = 0; c < 4; ++c) u[c] = ou[(size_t)(b * 4 + c) * 4096 + t];
    const float binv = 1.21267812518f;  // 1/sqrt(0.2^2+0.8^2)
#pragma unroll
    for (int c = 0; c < 4; ++c) {
        float s = 0.f;
#pragma unroll
        for (int j = 0; j < 4; ++j) s += wo[c * 4 + j] * oo[j];
        s *= so[c];
        a[c] = (0.2f * u[c] + 0.8f * s) * binv;
    }
    float mvec[4];
#pragma unroll
    for (int o = 0; o < 4; ++o) {
        float s = 0.f;
#pragma unroll
        for (int c = 0; c < 4; ++c) s += gw1[o * 8 + c] * u[c] + gw1[o * 8 + 4 + c] * a[c];
        mvec[o] = mp_silu_f(s * s1[o]);
    }
    float g0 = 0.f, g1 = 0.f;
#pragma unroll
    for (int o = 0; o < 4; ++o) { g0 += gw2[o] * mvec[o]; g1 += gw2[4 + o] * mvec[o]; }
    g0 *= s2[0]; g1 *= s2[1];
    float mx = fmaxf(g0, g1);
    float e0 = expf(g0 - mx), e1 = expf(g1 - mx);
    float invd = 1.f / (e0 + e1);
    g0 = e0 * invd; g1 = e1 * invd;
#pragma unroll
    for (int c = 0; c < 4; ++c)
        out[(size_t)(b * 4 + c) * 4096 + t] = g0 * u[c] + g1 * a[c];
}

// ---------------------------------------------------------------------------
extern "C" void kernel_launch(void* const* d_in, const int* in_sizes, int n_in,
                              void* d_out, int out_size, void* d_ws, size_t ws_size,
                              hipStream_t stream) {
    (void)in_sizes; (void)n_in; (void)out_size; (void)ws_size;

    const float* x        = (const float*)d_in[0];
    const float* time_vec = (const float*)d_in[1];
    const float* text_emb = (const float*)d_in[2];
    const float* zeta     = (const float*)d_in[5];
    const float* f_freq   = (const float*)d_in[6];
    const float* f_phase  = (const float*)d_in[7];
    const float* w_f1     = (const float*)d_in[8];
    const float* w_f2     = (const float*)d_in[9];
    const float* w_scale  = (const float*)d_in[10];
    const float* w_ru     = (const float*)d_in[11];
    const float* w_rv     = (const float*)d_in[12];
    const float* uw_in    = (const float*)d_in[13];
    const float* uw_time  = (const float*)d_in[14];
    const float* uw_mid   = (const float*)d_in[15];
    const float* uw_out   = (const float*)d_in[16];
    const float* vw_patch = (const float*)d_in[17];
    const float* v_pos    = (const float*)d_in[18];
    const float* vw_qkv   = (const float*)d_in[19];
    const float* vw_proj  = (const float*)d_in[20];
    const float* vw_time  = (const float*)d_in[21];
    const float* vw_text  = (const float*)d_in[22];
    const float* vw_mlp1  = (const float*)d_in[23];
    const float* vw_mlp2  = (const float*)d_in[24];
    const float* vw_unp   = (const float*)d_in[25];
    const float* ca_wq    = (const float*)d_in[26];
    const float* ca_wk    = (const float*)d_in[27];
    const float* ca_wv    = (const float*)d_in[28];
    const float* ca_wo    = (const float*)d_in[29];
    const float* gw1      = (const float*)d_in[30];
    const float* gw2      = (const float*)d_in[31];

    float* out = (float*)d_out;

    float* Wp = (float*)d_ws;
    size_t off = 0;
    auto alloc = [&](size_t n) { float* p = Wp + off; off += (n + 3) & ~(size_t)3; return p; };

    float* s_wf1   = alloc(1024);
    float* s_wf2   = alloc(512);
    float* s_wsc   = alloc(2);
    float* s_wru   = alloc(4);
    float* s_wrv   = alloc(4);
    float* s_uwin  = alloc(768);
    float* s_uwt   = alloc(768);
    float* s_uwm   = alloc(768);
    float* s_uwo   = alloc(16);
    float* s_vwp   = alloc(2048);
    float* s_vwqkv = alloc(6144);
    float* s_vwpr  = alloc(2048);
    float* s_vwti  = alloc(2048);
    float* s_vwte  = alloc(2048);
    float* s_vwm1  = alloc(8192);
    float* s_vwm2  = alloc(2048);
    float* s_vwun  = alloc(1024);
    float* s_cawq  = alloc(4);
    float* s_cawk  = alloc(4);
    float* s_cawv  = alloc(4);
    float* s_cawo  = alloc(4);
    float* s_gw1   = alloc(4);
    float* s_gw2   = alloc(2);

    float* femb    = alloc(1024);
    float* h1      = alloc(4096);
    float* temb    = alloc(2048);
    float* scale2  = alloc(8);
    float* mean_x  = alloc(16);
    int*   eidx    = (int*)alloc(8);
    float* gain    = alloc(8);
    float* rwv     = alloc(16);
    float* textp   = alloc(3072);
    float* tvec    = alloc(3072);      // [4b][4e*192]
    float* patchtok= alloc(65536);
    float* in_unet = alloc(65536);
    float* in_vit  = alloc(65536);
    float* out_unet= alloc(65536);
    float* out_vit = alloc(65536);
    float* vcond   = alloc(8192);      // [4b][4e*512]
    unsigned short* wtmid = (unsigned short*)alloc(663552);   // [4e][9][192][192] bf16

    // union region: UNet slot buffers alias the ViT intermediates (the stream
    // fully serializes UNet convs before the ViT stack, so aliasing is safe).
    float* region  = alloc(6291456);
    unsigned short* bufA = (unsigned short*)region;                  // [8 slots][64][64][192] bf16
    unsigned short* bufB = (unsigned short*)(region + 3145728);
    float* vtok  = region + 0;         // [4e][256][512]
    float* vqkv  = region + 524288;    // [4e][256][1536]
    float* vao   = region + 2097152;   // [4e][256][512]
    float* vtok2 = region + 2621440;   // [4e][256][512]
    float* vhid  = region + 3145728;   // [4e][256][2048]
    float* vtok3 = region + 5242880;   // [4e][256][512]
    float* vout  = region + 5767168;   // [4e][256][256]

    float* caq     = alloc(65536);
    float* cak     = alloc(65536);
    float* cav     = alloc(65536);
    float* cao     = alloc(65536);

    // ---- merged rowscale
    RsTab tab;
    int rowCounts[23] = {1024, 512, 2, 4, 4, 768, 768, 768, 16, 2048, 6144, 2048,
                         2048, 2048, 8192, 2048, 1024, 4, 4, 4, 4, 4, 2};
    const float* srcs[23] = {w_f1, w_f2, w_scale, w_ru, w_rv, uw_in, uw_time, uw_mid, uw_out,
                             vw_patch, vw_qkv, vw_proj, vw_time, vw_text, vw_mlp1, vw_mlp2,
                             vw_unp, ca_wq, ca_wk, ca_wv, ca_wo, gw1, gw2};
    float* dsts[23] = {s_wf1, s_wf2, s_wsc, s_wru, s_wrv, s_uwin, s_uwt, s_uwm, s_uwo,
                       s_vwp, s_vwqkv, s_vwpr, s_vwti, s_vwte, s_vwm1, s_vwm2,
                       s_vwun, s_cawq, s_cawk, s_cawv, s_cawo, s_gw1, s_gw2};
    int fans[23] = {256, 1024, 512, 516, 516, 36, 512, 1728, 1728, 256, 512, 512,
                    512, 768, 512, 2048, 512, 4, 4, 4, 4, 8, 4};
    int cum = 0;
    for (int i = 0; i < 23; ++i) {
        tab.e[i].w = srcs[i]; tab.e[i].o = dsts[i];
        tab.e[i].fan = fans[i]; tab.e[i].rowStart = cum;
        cum += rowCounts[i];
    }
    rowscale_all_kernel<<<dim3(cum), dim3(256), 0, stream>>>(tab);
    wmid_cvt_kernel<<<dim3((1327104 + 255) / 256), dim3(256), 0, stream>>>(uw_mid, wtmid);

    auto gemv = [&](int ACT, int HASRES, const float* A, const float* W2, const float* wsc,
                    const float* res, float osc, float* o, int M, int N, int K) {
        dim3 g(M * N / 4);
        if (ACT)
            gemv_kernel<1, 0><<<g, 256, 0, stream>>>(A, W2, wsc, res, osc, o, N, K);
        else if (HASRES)
            gemv_kernel<0, 1><<<g, 256, 0, stream>>>(A, W2, wsc, res, osc, o, N, K);
        else
            gemv_kernel<0, 0><<<g, 256, 0, stream>>>(A, W2, wsc, res, osc, o, N, K);
    };

    // ---- time embedding chain
    femb_kernel<<<dim3(4), dim3(256), 0, stream>>>(time_vec, f_freq, f_phase, femb);
    gemv(1, 0, femb, w_f1, s_wf1, nullptr, 1.f, h1, 4, 1024, 256);
    gemv(0, 0, h1, w_f2, s_wf2, nullptr, 1.f, temb, 4, 512, 1024);

    scale_kernel<<<dim3(1), dim3(64), 0, stream>>>(temb, w_scale, s_wsc, zeta, scale2);
    meanx_kernel<<<dim3(16), dim3(256), 0, stream>>>(x, mean_x);
    router_kernel<<<dim3(1), dim3(64), 0, stream>>>(mean_x, scale2, temb, w_ru, s_wru, w_rv, s_wrv,
                                                    zeta, eidx, gain, rwv, out + 65536);
    make_inputs_kernel<<<dim3(256), dim3(256), 0, stream>>>(x, scale2, in_vit, in_unet);
    textp_kernel<<<dim3(12), dim3(256), 0, stream>>>(text_emb, textp);
    patchify_kernel<<<dim3(256), dim3(256), 0, stream>>>(in_vit, patchtok);

    // per-expert UNet time mod: tvec [4b][4e*192]
    gemv(0, 0, temb, uw_time, s_uwt, nullptr, 1.f, tvec, 4, 768, 512);

    hipMemsetAsync(out_unet, 0, 65536 * sizeof(float), stream);

    // ---- UNet conv chain, slot-compacted
    conv_in_kernel<<<dim3(16, 24, 8), dim3(256), 0, stream>>>(
        in_unet, uw_in, s_uwin, tvec, eidx, bufA);
    conv_mid_mfma<<<dim3(32, 3, 8), dim3(256), 0, stream>>>(
        bufA, wtmid, s_uwm, eidx, bufB);
    conv_out_kernel<<<dim3(16, 8, 8), dim3(256), 0, stream>>>(
        bufB, uw_out, s_uwo, eidx, gain, out_unet);

    // ---- ViT cond vectors: vcond [4b][4e*512]
    gemv(0, 0, temb, vw_time, s_vwti, nullptr, 1.f, vcond, 4, 2048, 512);
    gemv(0, 1, textp, vw_text, s_vwte, vcond, 1.f, vcond, 4, 2048, 768);

    auto mlin = [&](int ACT, const float* A, int aE, const float* W2, int wE2,
                    const float* wsc, int wscE, const float* pos, int posE,
                    const float* cond, int condRow, int condE,
                    const float* res, int resE, float osc,
                    const float* gate, float* o, int outE, int M, int N, int K) {
        dim3 g(N / 64, M / 64, 4);
        if (ACT)
            mfma_linear_kernel<1><<<g, 256, 0, stream>>>(A, aE, W2, wE2, wsc, wscE, pos, posE,
                                                         cond, condRow, condE, res, resE, osc,
                                                         gate, o, outE, M, N, K);
        else
            mfma_linear_kernel<0><<<g, 256, 0, stream>>>(A, aE, W2, wE2, wsc, wscE, pos, posE,
                                                         cond, condRow, condE, res, resE, osc,
                                                         gate, o, outE, M, N, K);
    };

    // ---- ViT expert stack
    mlin(0, patchtok, 0, vw_patch, 131072, s_vwp, 512, v_pos, 32768,
         vcond, 2048, 512, nullptr, 0, 1.f, rwv, vtok, 131072, 256, 512, 256);
    mlin(0, vtok, 131072, vw_qkv, 786432, s_vwqkv, 1536, nullptr, 0,
         nullptr, 0, 0, nullptr, 0, 1.f, rwv, vqkv, 393216, 256, 1536, 512);
    vit_attn_kernel<<<dim3(128), dim3(64), 0, stream>>>(vqkv, rwv, vao);
    mlin(0, vao, 131072, vw_proj, 262144, s_vwpr, 512, nullptr, 0,
         nullptr, 0, 0, vtok, 131072, 0.70710678f, rwv, vtok2, 131072, 256, 512, 512);
    mlin(1, vtok2, 131072, vw_mlp1, 1048576, s_vwm1, 2048, nullptr, 0,
         nullptr, 0, 0, nullptr, 0, 1.f, rwv, vhid, 524288, 256, 2048, 512);
    mlin(0, vhid, 524288, vw_mlp2, 1048576, s_vwm2, 512, nullptr, 0,
         nullptr, 0, 0, vtok2, 131072, 0.70710678f, rwv, vtok3, 131072, 256, 512, 2048);
    mlin(0, vtok3, 131072, vw_unp, 131072, s_vwun, 256, nullptr, 0,
         nullptr, 0, 0, nullptr, 0, 1.f, rwv, vout, 65536, 256, 256, 512);
    unpatch_scatter_kernel<<<dim3(256), dim3(256), 0, stream>>>(vout, rwv, out_vit);

    // ---- cross attention + fused tail
    ca_qkv_kernel<<<dim3(64), dim3(256), 0, stream>>>(out_unet, out_vit, ca_wq, s_cawq,
                                                      ca_wk, s_cawk, ca_wv, s_cawv, caq, cak, cav);
    ca_attn_kernel<<<dim3(256), dim3(512), 0, stream>>>(caq, cak, cav, cao);
    ca_final_kernel<<<dim3(64), dim3(256), 0, stream>>>(cao, out_unet, ca_wo, s_cawo,
                                                        gw1, s_gw1, gw2, s_gw2, out);
}

// Round 5
// 418.524 us; speedup vs baseline: 1.3284x; 1.3284x over previous
//
#include <hip/hip_runtime.h>
#include <math.h>

// ---------------------------------------------------------------------------
// HDMOEM round 5: software-pipelined bf16-activation MFMA GEMM (T14 prefetch),
// bf16 ViT intermediates, scale-folded mid-conv weights.
// B=4, C=4, H=W=64, E=4 experts/path, TOPK=2. Router masks all-True, ignored.
// ---------------------------------------------------------------------------

#define DEV_INLINE __device__ __forceinline__

typedef __attribute__((ext_vector_type(8))) short bf16x8;
typedef __attribute__((ext_vector_type(4))) float f32x4;

DEV_INLINE float mp_silu_f(float x) { return x / ((1.f + __expf(-x)) * 0.596f); }

DEV_INLINE unsigned short f2bf(float x) {
    unsigned u = __float_as_uint(x);
    unsigned r = (u + 0x7fffu + ((u >> 16) & 1u)) >> 16;
    return (unsigned short)r;
}
DEV_INLINE float bf2f(unsigned short u) { return __uint_as_float(((unsigned)u) << 16); }
DEV_INLINE float bflo(unsigned u) { return __uint_as_float(u << 16); }
DEV_INLINE float bfhi(unsigned u) { return __uint_as_float(u & 0xffff0000u); }

// ---------------------------------------------------------------------------
struct RsEnt { const float* w; float* o; int fan; int rowStart; };
struct RsTab { RsEnt e[23]; };

__global__ void rowscale_all_kernel(RsTab t) {
    int r = blockIdx.x;
    int ti = 0;
#pragma unroll
    for (int j = 1; j < 23; ++j)
        if (r >= t.e[j].rowStart) ti = j;
    const float* p = t.e[ti].w;
    int fan = t.e[ti].fan;
    int row = r - t.e[ti].rowStart;
    p += (size_t)row * fan;
    float s = 0.f;
    for (int i = threadIdx.x; i < fan; i += 256) { float v = p[i]; s += v * v; }
    __shared__ float red[256];
    red[threadIdx.x] = s;
    __syncthreads();
    for (int st = 128; st > 0; st >>= 1) {
        if (threadIdx.x < st) red[threadIdx.x] += red[threadIdx.x + st];
        __syncthreads();
    }
    if (threadIdx.x == 0) {
        float mean = red[0] / (float)fan;
        t.e[ti].o[row] = 1.f / sqrtf((mean + 1e-8f) * (float)fan);
    }
}

// ---- mid-conv weights: [e][oc][ic][3][3] f32 -> [e][tap][oc][ic] bf16, *wsc folded
__global__ void wmid_cvt_kernel(const float* __restrict__ w, const float* __restrict__ wsc,
                                unsigned short* __restrict__ wt) {
    int i = blockIdx.x * 256 + threadIdx.x;
    if (i >= 4 * 9 * 192 * 192) return;
    int ic = i % 192;
    int t = i / 192;
    int oc = t % 192; t /= 192;
    int tap = t % 9;
    int e = t / 9;
    wt[i] = f2bf(w[(((size_t)(e * 192 + oc) * 192 + ic) * 9) + tap] * wsc[e * 192 + oc]);
}

__global__ void femb_kernel(const float* __restrict__ tv, const float* __restrict__ fr,
                            const float* __restrict__ ph, float* __restrict__ femb) {
    int i = blockIdx.x * 256 + threadIdx.x;
    if (i >= 1024) return;
    int b = i >> 8, j = i & 255;
    femb[i] = 1.41421356237f * cosf(6.28318530717958647f * (tv[b] * fr[j] + ph[j]));
}

// ---- wave-per-output GEMV for small-M linears
template <int ACT, int HASRES>
__global__ void gemv_kernel(const float* __restrict__ A, const float* __restrict__ W,
                            const float* __restrict__ wsc, const float* __restrict__ res,
                            float osc, float* __restrict__ out, int N, int K) {
    int o = blockIdx.x * 4 + (threadIdx.x >> 6);
    int lane = threadIdx.x & 63;
    int m = o / N, n = o % N;
    const float* a = A + (size_t)m * K;
    const float* w = W + (size_t)n * K;
    float s = 0.f;
    for (int k = lane; k < K; k += 64) s += a[k] * w[k];
#pragma unroll
    for (int sh = 32; sh > 0; sh >>= 1) s += __shfl_xor(s, sh);
    if (lane == 0) {
        float val = s * wsc[n];
        if (ACT) val = mp_silu_f(val);
        if (HASRES) val = (val + res[(size_t)m * N + n]) * osc;
        out[(size_t)m * N + n] = val;
    }
}

__global__ void scale_kernel(const float* __restrict__ temb, const float* __restrict__ w,
                             const float* __restrict__ wsc, const float* __restrict__ zeta,
                             float* __restrict__ scale2) {
    __shared__ float lg[8];
    int t = threadIdx.x;
    if (t < 8) {
        int b = t >> 1, o = t & 1;
        float s = 0.f;
        for (int k = 0; k < 512; ++k) s += temb[b * 512 + k] * w[o * 512 + k];
        lg[t] = s * wsc[o] / zeta[0];
    }
    __syncthreads();
    if (t < 4) {
        float a = lg[t * 2], b2 = lg[t * 2 + 1];
        float m = fmaxf(a, b2);
        float e0 = expf(a - m), e1 = expf(b2 - m);
        float inv = 2.f / (e0 + e1);
        scale2[t * 2] = e0 * inv;
        scale2[t * 2 + 1] = e1 * inv;
    }
}

__global__ void meanx_kernel(const float* __restrict__ x, float* __restrict__ mean_x) {
    int bc = blockIdx.x;
    float s = 0.f;
    for (int i = threadIdx.x; i < 4096; i += 256) s += x[bc * 4096 + i];
    __shared__ float red[256];
    red[threadIdx.x] = s;
    __syncthreads();
    for (int st = 128; st > 0; st >>= 1) {
        if (threadIdx.x < st) red[threadIdx.x] += red[threadIdx.x + st];
        __syncthreads();
    }
    if (threadIdx.x == 0) mean_x[bc] = red[0] * (1.f / 4096.f);
}

// ---- routers: probs + top2; unet side also emits slot tables (eidx, gain)
__global__ void router_kernel(const float* __restrict__ mean_x, const float* __restrict__ scale2,
                              const float* __restrict__ temb,
                              const float* __restrict__ wu, const float* __restrict__ su,
                              const float* __restrict__ wv, const float* __restrict__ sv,
                              const float* __restrict__ zeta,
                              int* __restrict__ eidx, float* __restrict__ gain,
                              float* __restrict__ rwv,
                              float* __restrict__ probs_out) {
    __shared__ float lg[2][4][4];
    int t = threadIdx.x;
    if (t < 32) {
        int r = t >> 4, b = (t >> 2) & 3, e = t & 3;
        const float* w = (r == 0) ? wu : wv;
        const float* sc = (r == 0) ? su : sv;
        float ps = scale2[b * 2 + (r == 0 ? 1 : 0)];
        float acc = 0.f;
        for (int c = 0; c < 4; ++c) acc += mean_x[b * 4 + c] * ps * w[e * 516 + c];
        for (int j = 0; j < 512; ++j) acc += temb[b * 512 + j] * w[e * 516 + 4 + j];
        lg[r][b][e] = acc * sc[e] / zeta[0];
    }
    __syncthreads();
    if (t < 8) {
        int r = t >> 2, b = t & 3;
        float p[4];
        float mx = -1e30f;
        for (int e = 0; e < 4; ++e) mx = fmaxf(mx, lg[r][b][e]);
        float sum = 0.f;
        for (int e = 0; e < 4; ++e) { p[e] = expf(lg[r][b][e] - mx); sum += p[e]; }
        for (int e = 0; e < 4; ++e) p[e] /= sum;
        int i1 = 0;
        for (int e = 1; e < 4; ++e) if (p[e] > p[i1]) i1 = e;
        int i2 = -1;
        for (int e = 0; e < 4; ++e) { if (e == i1) continue; if (i2 < 0 || p[e] > p[i2]) i2 = e; }
        float inv = 1.f / (p[i1] + p[i2]);
        if (r == 0) {
            eidx[b * 2] = i1; eidx[b * 2 + 1] = i2;
            gain[b * 2] = p[i1] * inv; gain[b * 2 + 1] = p[i2] * inv;
        } else {
            for (int e = 0; e < 4; ++e) rwv[b * 4 + e] = 0.f;
            rwv[b * 4 + i1] = p[i1] * inv;
            rwv[b * 4 + i2] = p[i2] * inv;
        }
        for (int e = 0; e < 4; ++e) probs_out[r * 16 + b * 4 + e] = p[e];
    }
}

__global__ void make_inputs_kernel(const float* __restrict__ x, const float* __restrict__ scale2,
                                   float* __restrict__ in_vit, float* __restrict__ in_unet) {
    int i = blockIdx.x * 256 + threadIdx.x;
    if (i >= 65536) return;
    int b = i >> 14;
    float v = x[i];
    in_vit[i] = scale2[b * 2] * v;
    in_unet[i] = scale2[b * 2 + 1] * v;
}

__global__ void textp_kernel(const float* __restrict__ te, float* __restrict__ tp) {
    int i = blockIdx.x * 256 + threadIdx.x;
    if (i >= 3072) return;
    int b = i / 768, f = i % 768;
    float s = 0.f;
    for (int t = 0; t < 77; ++t) s += te[(size_t)(b * 77 + t) * 768 + f];
    tp[i] = s * (1.f / 77.f);
}

// ---- patchify -> bf16 tokens [B,64,256]
__global__ void patchify_kernel(const float* __restrict__ in_vit, unsigned short* __restrict__ pt) {
    int i = blockIdx.x * 256 + threadIdx.x;
    if (i >= 65536) return;
    int b = i >> 14;
    int r = i & 16383;
    int s = r >> 8, f = r & 255;
    int c = f >> 6, py = (f >> 3) & 7, px = f & 7;
    int gy = s >> 3, gx = s & 7;
    pt[i] = f2bf(in_vit[((b * 4 + c) * 64 + gy * 8 + py) * 64 + gx * 8 + px]);
}

// ---------------------------------------------------------------------------
// conv_in (slots): NCHW f32 -> NHWC bf16 per slot. grid (16,24,8)
__global__ void conv_in_kernel(const float* __restrict__ in, const float* __restrict__ wbase,
                               const float* __restrict__ wscb, const float* __restrict__ tvec,
                               const int* __restrict__ eidx,
                               unsigned short* __restrict__ out) {
    int z = blockIdx.z, b = z >> 1;
    int e = eidx[z];
    const float* w = wbase + (size_t)e * 6912;
    const float* wsc = wscb + e * 192;
    const float* tmod = tvec + b * 768 + e * 192;
    int tileIdx = blockIdx.x;
    int ty0 = (tileIdx >> 2) * 16, tx0 = (tileIdx & 3) * 16;
    int oc0 = blockIdx.y * 8;
    int lty = threadIdx.x >> 4, ltx = threadIdx.x & 15;
    int y = ty0 + lty, x = tx0 + ltx;
    __shared__ float tile[4][18][18];
    for (int i = threadIdx.x; i < 4 * 18 * 18; i += 256) {
        int ic = i / 324, rr = (i / 18) % 18, cc = i % 18;
        int gy = ty0 - 1 + rr, gx = tx0 - 1 + cc;
        float v = 0.f;
        if (gy >= 0 && gy < 64 && gx >= 0 && gx < 64)
            v = in[((b * 4 + ic) * 64 + gy) * 64 + gx];
        tile[ic][rr][cc] = v;
    }
    __syncthreads();
    float win[4][9];
#pragma unroll
    for (int ic = 0; ic < 4; ++ic)
#pragma unroll
        for (int ky = 0; ky < 3; ++ky)
#pragma unroll
            for (int kx = 0; kx < 3; ++kx)
                win[ic][ky * 3 + kx] = tile[ic][lty + ky][ltx + kx];
#pragma unroll
    for (int o = 0; o < 8; ++o) {
        int oc = oc0 + o;
        float acc = 0.f;
#pragma unroll
        for (int ic = 0; ic < 4; ++ic) {
            const float* wp = w + (size_t)(oc * 4 + ic) * 9;
#pragma unroll
            for (int kk = 0; kk < 9; ++kk) acc += wp[kk] * win[ic][kk];
        }
        float val = acc * wsc[oc] * (1.f + tmod[oc]);
        val = mp_silu_f(val);
        out[((z * 64 + y) * 64 + x) * 192 + oc] = f2bf(val);
    }
}

// ---------------------------------------------------------------------------
// mid conv (slots): implicit-GEMM bf16 MFMA, scale folded in wt. grid (32,3,8)
__global__ __launch_bounds__(256) void conv_mid_mfma(
    const unsigned short* __restrict__ in, const unsigned short* __restrict__ wtbase,
    const int* __restrict__ eidx,
    unsigned short* __restrict__ out) {
    int z = blockIdx.z;
    int e = eidx[z];
    const unsigned short* wt = wtbase + (size_t)e * 331776;
    int y0 = blockIdx.x * 2;
    int oc0 = blockIdx.y * 64;
    int wid = threadIdx.x >> 6, lane = threadIdx.x & 63;
    int wm = wid >> 1, wn = wid & 1;
    int l15 = lane & 15, lq = lane >> 4;

    __shared__ unsigned short Alds[4 * 66 * 40];
    f32x4 acc[4][2];
#pragma unroll
    for (int g = 0; g < 4; ++g)
#pragma unroll
        for (int f = 0; f < 2; ++f) acc[g][f] = (f32x4){0.f, 0.f, 0.f, 0.f};

    for (int icc = 0; icc < 6; ++icc) {
        int ic0 = icc * 32;
        for (int i = threadIdx.x; i < 1056; i += 256) {
            int q = i & 3;
            int xx = (i >> 2) % 66;
            int r = (i >> 2) / 66;
            int y = y0 - 1 + r, xg = xx - 1;
            uint4 val = {0u, 0u, 0u, 0u};
            if (y >= 0 && y < 64 && xg >= 0 && xg < 64)
                val = *(const uint4*)&in[((z * 64 + y) * 64 + xg) * 192 + ic0 + q * 8];
            *(uint4*)&Alds[(r * 66 + xx) * 40 + q * 8] = val;
        }
        __syncthreads();
#pragma unroll
        for (int tap = 0; tap < 9; ++tap) {
            int ky = tap / 3, kx = tap % 3;
            bf16x8 bfr[2];
#pragma unroll
            for (int fn = 0; fn < 2; ++fn) {
                int oc = oc0 + wn * 32 + fn * 16 + l15;
                bfr[fn] = *(const bf16x8*)&wt[(size_t)(tap * 192 + oc) * 192 + ic0 + 8 * lq];
            }
            int r = wm + ky;
#pragma unroll
            for (int g = 0; g < 4; ++g) {
                int xx = g * 16 + l15 + kx;
                bf16x8 afr = *(const bf16x8*)&Alds[(r * 66 + xx) * 40 + 8 * lq];
                acc[g][0] = __builtin_amdgcn_mfma_f32_16x16x32_bf16(afr, bfr[0], acc[g][0], 0, 0, 0);
                acc[g][1] = __builtin_amdgcn_mfma_f32_16x16x32_bf16(afr, bfr[1], acc[g][1], 0, 0, 0);
            }
        }
        __syncthreads();
    }
    int orow = y0 + wm;
#pragma unroll
    for (int g = 0; g < 4; ++g)
#pragma unroll
        for (int fn = 0; fn < 2; ++fn) {
            int oc = oc0 + wn * 32 + fn * 16 + l15;
#pragma unroll
            for (int r2 = 0; r2 < 4; ++r2) {
                int px = g * 16 + lq * 4 + r2;
                float v = mp_silu_f(acc[g][fn][r2]);
                out[((z * 64 + orow) * 64 + px) * 192 + oc] = f2bf(v);
            }
        }
}

// ---------------------------------------------------------------------------
// conv_out (slots, split-K): grid (16 tiles, 8 kchunks, 8 slots), atomicAdd.
__global__ __launch_bounds__(256) void conv_out_kernel(
    const unsigned short* __restrict__ in, const float* __restrict__ wbase,
    const float* __restrict__ wscb, const int* __restrict__ eidx,
    const float* __restrict__ gain, float* __restrict__ out) {
    int z = blockIdx.z, b = z >> 1;
    int e = eidx[z];
    float g = gain[z];
    const float* w = wbase + (size_t)e * 6912;
    const float* wsc = wscb + e * 4;
    int c0 = blockIdx.y * 24;
    int tileIdx = blockIdx.x;
    int ty0 = (tileIdx >> 2) * 16, tx0 = (tileIdx & 3) * 16;
    int lty = threadIdx.x >> 4, ltx = threadIdx.x & 15;
    int y = ty0 + lty, x = tx0 + ltx;
    __shared__ float tile[24][18][18];
    for (int i = threadIdx.x; i < 972; i += 256) {
        int q = i % 3, cell = i / 3;
        int rr = cell / 18, cc = cell % 18;
        int gy = ty0 - 1 + rr, gx = tx0 - 1 + cc;
        uint4 raw = {0u, 0u, 0u, 0u};
        if (gy >= 0 && gy < 64 && gx >= 0 && gx < 64)
            raw = *(const uint4*)&in[((z * 64 + gy) * 64 + gx) * 192 + c0 + q * 8];
        int icb = q * 8;
        tile[icb + 0][rr][cc] = bflo(raw.x);
        tile[icb + 1][rr][cc] = bfhi(raw.x);
        tile[icb + 2][rr][cc] = bflo(raw.y);
        tile[icb + 3][rr][cc] = bfhi(raw.y);
        tile[icb + 4][rr][cc] = bflo(raw.z);
        tile[icb + 5][rr][cc] = bfhi(raw.z);
        tile[icb + 6][rr][cc] = bflo(raw.w);
        tile[icb + 7][rr][cc] = bfhi(raw.w);
    }
    __syncthreads();
    float acc[4] = {0.f, 0.f, 0.f, 0.f};
#pragma unroll
    for (int ic = 0; ic < 24; ++ic) {
        float win[9];
#pragma unroll
        for (int ky = 0; ky < 3; ++ky)
#pragma unroll
            for (int kx = 0; kx < 3; ++kx)
                win[ky * 3 + kx] = tile[ic][lty + ky][ltx + kx];
#pragma unroll
        for (int o = 0; o < 4; ++o) {
            const float* wp = w + (size_t)(o * 192 + c0 + ic) * 9;
#pragma unroll
            for (int kk = 0; kk < 9; ++kk) acc[o] += wp[kk] * win[kk];
        }
    }
#pragma unroll
    for (int o = 0; o < 4; ++o)
        atomicAdd(&out[((b * 4 + o) * 64 + y) * 64 + x], g * acc[o] * wsc[o]);
}

// ---------------------------------------------------------------------------
// bf16 MFMA linear v3: A bf16 [M,K], W f32 [N,K] (converted on stage), software
// pipelined (prefetch tile k+1 to regs before MFMA of tile k -> latency hides
// under compute). BM=64, BN=64, 4 waves 2x2 of 32x32. grid (N/64, M/64, E).
template <int ACT>
__global__ __launch_bounds__(256) void mfma_linear_kernel(
    const unsigned short* __restrict__ A, int aE,
    const float* __restrict__ W, int wE,
    const float* __restrict__ wsc, int wscE,
    const float* __restrict__ pos, int posE,
    const float* __restrict__ cond, int condRow, int condE,
    const unsigned short* __restrict__ res, int resE, float outscale,
    const float* __restrict__ gate,
    unsigned short* __restrict__ outp, int outE,
    int M, int N, int K) {
    int e = blockIdx.z;
    int bm = blockIdx.y * 64, bn = blockIdx.x * 64;
    if (gate && gate[(bm >> 6) * 4 + e] == 0.f) return;
    A += (size_t)e * aE;
    W += (size_t)e * wE;
    wsc += (size_t)e * wscE;
    if (pos) pos += (size_t)e * posE;
    if (cond) cond += (size_t)e * condE;
    if (res) res += (size_t)e * resE;
    outp += (size_t)e * outE;

    int tid = threadIdx.x;
    int wid = tid >> 6, lane = tid & 63;
    int wm = wid >> 1, wn = wid & 1;
    int l15 = lane & 15, lq = lane >> 4;
    __shared__ unsigned short Al[64 * 72];
    __shared__ unsigned short Wl[64 * 72];
    f32x4 acc[2][2];
#pragma unroll
    for (int mf = 0; mf < 2; ++mf)
#pragma unroll
        for (int nf = 0; nf < 2; ++nf) acc[mf][nf] = (f32x4){0.f, 0.f, 0.f, 0.f};

    // staging assignments
    int ar = tid >> 3, ac = (tid & 7) * 8;        // A: rows ar, ar+32; 8 bf16 chunks
    int wr = tid >> 4, wc = (tid & 15) * 4;       // W: rows wr,+16,+32,+48; 4 f32 chunks
    uint4 pa0, pa1;
    float4 pw0, pw1, pw2, pw3;

    auto gload = [&](int k0) {
        pa0 = *(const uint4*)&A[(size_t)(bm + ar) * K + k0 + ac];
        pa1 = *(const uint4*)&A[(size_t)(bm + ar + 32) * K + k0 + ac];
        pw0 = *(const float4*)&W[(size_t)(bn + wr) * K + k0 + wc];
        pw1 = *(const float4*)&W[(size_t)(bn + wr + 16) * K + k0 + wc];
        pw2 = *(const float4*)&W[(size_t)(bn + wr + 32) * K + k0 + wc];
        pw3 = *(const float4*)&W[(size_t)(bn + wr + 48) * K + k0 + wc];
    };
    auto sstore = [&]() {
        *(uint4*)&Al[ar * 72 + ac] = pa0;
        *(uint4*)&Al[(ar + 32) * 72 + ac] = pa1;
        ushort4 s;
        s.x = f2bf(pw0.x); s.y = f2bf(pw0.y); s.z = f2bf(pw0.z); s.w = f2bf(pw0.w);
        *(ushort4*)&Wl[wr * 72 + wc] = s;
        s.x = f2bf(pw1.x); s.y = f2bf(pw1.y); s.z = f2bf(pw1.z); s.w = f2bf(pw1.w);
        *(ushort4*)&Wl[(wr + 16) * 72 + wc] = s;
        s.x = f2bf(pw2.x); s.y = f2bf(pw2.y); s.z = f2bf(pw2.z); s.w = f2bf(pw2.w);
        *(ushort4*)&Wl[(wr + 32) * 72 + wc] = s;
        s.x = f2bf(pw3.x); s.y = f2bf(pw3.y); s.z = f2bf(pw3.z); s.w = f2bf(pw3.w);
        *(ushort4*)&Wl[(wr + 48) * 72 + wc] = s;
    };

    int nk = K >> 6;
    gload(0);
    for (int kk = 0; kk < nk; ++kk) {
        sstore();
        __syncthreads();
        if (kk + 1 < nk) gload((kk + 1) << 6);   // prefetch: waited at next sstore
#pragma unroll
        for (int ks = 0; ks < 2; ++ks) {
            bf16x8 af[2], wf[2];
#pragma unroll
            for (int mf = 0; mf < 2; ++mf)
                af[mf] = *(const bf16x8*)&Al[(wm * 32 + mf * 16 + l15) * 72 + ks * 32 + lq * 8];
#pragma unroll
            for (int nf = 0; nf < 2; ++nf)
                wf[nf] = *(const bf16x8*)&Wl[(wn * 32 + nf * 16 + l15) * 72 + ks * 32 + lq * 8];
#pragma unroll
            for (int mf = 0; mf < 2; ++mf)
#pragma unroll
                for (int nf = 0; nf < 2; ++nf)
                    acc[mf][nf] = __builtin_amdgcn_mfma_f32_16x16x32_bf16(af[mf], wf[nf], acc[mf][nf], 0, 0, 0);
        }
        __syncthreads();
    }
#pragma unroll
    for (int mf = 0; mf < 2; ++mf)
#pragma unroll
        for (int nf = 0; nf < 2; ++nf) {
            int n = bn + wn * 32 + nf * 16 + l15;
            float ws = wsc[n];
#pragma unroll
            for (int r = 0; r < 4; ++r) {
                int m = bm + wm * 32 + mf * 16 + lq * 4 + r;
                float val = acc[mf][nf][r] * ws;
                if (pos) val += pos[(m & 63) * N + n];
                if (cond) val *= (1.f + cond[(m >> 6) * condRow + n]);
                if (ACT) val = mp_silu_f(val);
                if (res) val = (val + bf2f(res[(size_t)m * N + n])) * outscale;
                outp[(size_t)m * N + n] = f2bf(val);
            }
        }
}

// ---- ViT self-attention over (e,b,h); bf16 IO, vectorized loads
__global__ void vit_attn_kernel(const unsigned short* __restrict__ qkv_base,
                                const float* __restrict__ rwv,
                                unsigned short* __restrict__ out_base) {
    int e = blockIdx.x >> 5, b = (blockIdx.x >> 3) & 3, h = blockIdx.x & 7;
    if (rwv[b * 4 + e] == 0.f) return;
    const unsigned short* qkv = qkv_base + (size_t)e * 393216;
    unsigned short* out = out_base + (size_t)e * 131072;
    __shared__ float ks[64][68], vs[64][68], sc[64][65];
    int tid = threadIdx.x;
    for (int i = tid; i < 512; i += 64) {
        int j = i >> 3, c = (i & 7) * 8;
        const unsigned short* kp = &qkv[(size_t)(b * 64 + j) * 1536 + 512 + h * 64 + c];
        uint4 kr = *(const uint4*)kp;
        uint4 vr = *(const uint4*)(kp + 512);
        float* kd = &ks[j][c];
        float* vd = &vs[j][c];
        kd[0] = bflo(kr.x); kd[1] = bfhi(kr.x); kd[2] = bflo(kr.y); kd[3] = bfhi(kr.y);
        kd[4] = bflo(kr.z); kd[5] = bfhi(kr.z); kd[6] = bflo(kr.w); kd[7] = bfhi(kr.w);
        vd[0] = bflo(vr.x); vd[1] = bfhi(vr.x); vd[2] = bflo(vr.y); vd[3] = bfhi(vr.y);
        vd[4] = bflo(vr.z); vd[5] = bfhi(vr.z); vd[6] = bflo(vr.w); vd[7] = bfhi(vr.w);
    }
    float qreg[64];
#pragma unroll
    for (int c8 = 0; c8 < 8; ++c8) {
        uint4 qr = *(const uint4*)&qkv[(size_t)(b * 64 + tid) * 1536 + h * 64 + c8 * 8];
        qreg[c8 * 8 + 0] = bflo(qr.x); qreg[c8 * 8 + 1] = bfhi(qr.x);
        qreg[c8 * 8 + 2] = bflo(qr.y); qreg[c8 * 8 + 3] = bfhi(qr.y);
        qreg[c8 * 8 + 4] = bflo(qr.z); qreg[c8 * 8 + 5] = bfhi(qr.z);
        qreg[c8 * 8 + 6] = bflo(qr.w); qreg[c8 * 8 + 7] = bfhi(qr.w);
    }
    __syncthreads();
    float mx = -1e30f;
    for (int j = 0; j < 64; ++j) {
        float s = 0.f;
#pragma unroll
        for (int d4 = 0; d4 < 16; ++d4) {
            float4 kk = *(const float4*)&ks[j][d4 * 4];
            s += qreg[d4 * 4] * kk.x + qreg[d4 * 4 + 1] * kk.y +
                 qreg[d4 * 4 + 2] * kk.z + qreg[d4 * 4 + 3] * kk.w;
        }
        s *= 0.125f;
        sc[tid][j] = s;
        mx = fmaxf(mx, s);
    }
    float sum = 0.f;
    for (int j = 0; j < 64; ++j) { float ee = __expf(sc[tid][j] - mx); sc[tid][j] = ee; sum += ee; }
    float inv = 1.f / sum;
    float4 acc4[16];
#pragma unroll
    for (int d4 = 0; d4 < 16; ++d4) acc4[d4] = (float4){0.f, 0.f, 0.f, 0.f};
    for (int j = 0; j < 64; ++j) {
        float ee = sc[tid][j];
#pragma unroll
        for (int d4 = 0; d4 < 16; ++d4) {
            float4 vv = *(const float4*)&vs[j][d4 * 4];
            acc4[d4].x += ee * vv.x; acc4[d4].y += ee * vv.y;
            acc4[d4].z += ee * vv.z; acc4[d4].w += ee * vv.w;
        }
    }
    unsigned short* op = &out[(size_t)(b * 64 + tid) * 512 + h * 64];
#pragma unroll
    for (int d4 = 0; d4 < 16; ++d4) {
        ushort4 r;
        r.x = f2bf(acc4[d4].x * inv); r.y = f2bf(acc4[d4].y * inv);
        r.z = f2bf(acc4[d4].z * inv); r.w = f2bf(acc4[d4].w * inv);
        *(ushort4*)&op[d4 * 4] = r;
    }
}

__global__ void unpatch_scatter_kernel(const unsigned short* __restrict__ vout,
                                       const float* __restrict__ rwv,
                                       float* __restrict__ out_vit) {
    int i = blockIdx.x * 256 + threadIdx.x;
    if (i >= 65536) return;
    int b = i >> 14;
    int c = (i >> 12) & 3, y = (i >> 6) & 63, x = i & 63;
    int f = c * 64 + (y & 7) * 8 + (x & 7);
    int s = (y >> 3) * 8 + (x >> 3);
    int idx = (b * 64 + s) * 256 + f;
    float acc = 0.f;
#pragma unroll
    for (int e = 0; e < 4; ++e) {
        float g = rwv[b * 4 + e];
        if (g != 0.f) acc += g * bf2f(vout[e * 65536 + idx]);
    }
    out_vit[i] = acc;
}

__global__ void ca_qkv_kernel(const float* __restrict__ ou, const float* __restrict__ ov,
                              const float* __restrict__ wq, const float* __restrict__ sq,
                              const float* __restrict__ wk, const float* __restrict__ sk,
                              const float* __restrict__ wv, const float* __restrict__ sv,
                              float* __restrict__ q, float* __restrict__ kx, float* __restrict__ vx) {
    int i = blockIdx.x * 256 + threadIdx.x;
    if (i >= 16384) return;
    int b = i >> 12, t = i & 4095;
    float u[4], c[4];
#pragma unroll
    for (int cc = 0; cc < 4; ++cc) {
        u[cc] = ou[(size_t)(b * 4 + cc) * 4096 + t];
        c[cc] = ov[(size_t)(b * 4 + cc) * 4096 + t];
    }
#pragma unroll
    for (int o = 0; o < 4; ++o) {
        float aq = 0.f, ak = 0.f, av = 0.f;
#pragma unroll
        for (int cc = 0; cc < 4; ++cc) {
            aq += wq[o * 4 + cc] * u[cc];
            ak += wk[o * 4 + cc] * c[cc];
            av += wv[o * 4 + cc] * c[cc];
        }
        q[(size_t)(b * 4096 + t) * 4 + o] = aq * sq[o];
        kx[(size_t)(b * 4096 + t) * 4 + o] = ak * sk[o];
        vx[(size_t)(b * 4096 + t) * 4 + o] = av * sv[o];
    }
}

// ---- cross-attn: 8 key-segments x 8-key ILP batches, LDS merge
__global__ __launch_bounds__(512) void ca_attn_kernel(
    const float* __restrict__ q, const float* __restrict__ k,
    const float* __restrict__ v, float* __restrict__ o) {
    int b = blockIdx.x >> 6;
    int lq = threadIdx.x & 63, seg = threadIdx.x >> 6;
    int qt = ((blockIdx.x & 63) << 6) + lq;
    float4 qv = *(const float4*)&q[(size_t)(b * 4096 + qt) * 4];
    const float4* kb = (const float4*)(k + (size_t)b * 16384);
    const float4* vb = (const float4*)(v + (size_t)b * 16384);
    float m = -1e30f, l = 0.f, a0 = 0.f, a1 = 0.f, a2 = 0.f, a3 = 0.f;
    int j0 = seg * 512;
    for (int j = j0; j < j0 + 512; j += 8) {
        float s[8];
#pragma unroll
        for (int u = 0; u < 8; ++u) {
            float4 kk = kb[j + u];
            s[u] = 0.5f * (qv.x * kk.x + qv.y * kk.y + qv.z * kk.z + qv.w * kk.w);
        }
        float bm = fmaxf(fmaxf(fmaxf(s[0], s[1]), fmaxf(s[2], s[3])),
                         fmaxf(fmaxf(s[4], s[5]), fmaxf(s[6], s[7])));
        float nm = fmaxf(m, bm);
        float corr = __expf(m - nm);
        l *= corr; a0 *= corr; a1 *= corr; a2 *= corr; a3 *= corr;
#pragma unroll
        for (int u = 0; u < 8; ++u) {
            float ee = __expf(s[u] - nm);
            float4 vv = vb[j + u];
            l += ee;
            a0 += ee * vv.x; a1 += ee * vv.y; a2 += ee * vv.z; a3 += ee * vv.w;
        }
        m = nm;
    }
    __shared__ float red[8][64][8];
    red[seg][lq][0] = m; red[seg][lq][1] = l;
    red[seg][lq][2] = a0; red[seg][lq][3] = a1;
    red[seg][lq][4] = a2; red[seg][lq][5] = a3;
    __syncthreads();
    if (seg == 0) {
#pragma unroll
        for (int s2 = 1; s2 < 8; ++s2) {
            float m2 = red[s2][lq][0], l2 = red[s2][lq][1];
            float nm = fmaxf(m, m2);
            float c1 = __expf(m - nm), c2 = __expf(m2 - nm);
            l = l * c1 + l2 * c2;
            a0 = a0 * c1 + red[s2][lq][2] * c2;
            a1 = a1 * c1 + red[s2][lq][3] * c2;
            a2 = a2 * c1 + red[s2][lq][4] * c2;
            a3 = a3 * c1 + red[s2][lq][5] * c2;
            m = nm;
        }
        float inv = 1.f / l;
        float* op = &o[(size_t)(b * 4096 + qt) * 4];
        op[0] = a0 * inv; op[1] = a1 * inv; op[2] = a2 * inv; op[3] = a3 * inv;
    }
}

// ---- fused: out-proj + balanced blend + gated combine -> d_out
__global__ void ca_final_kernel(const float* __restrict__ ao, const float* __restrict__ ou,
                                const float* __restrict__ wo, const float* __restrict__ so,
                                const float* __restrict__ gw1, const float* __restrict__ s1,
                                const float* __restrict__ gw2, const float* __restrict__ s2,
                                float* __restrict__ out) {
    int i = blockIdx.x * 256 + threadIdx.x;
    if (i >= 16384) return;
    int b = i >> 12, t = i & 4095;
    float oo[4], u[4], a[4];
#pragma unroll
    for (int j = 0; j < 4; ++j) oo[j] = ao[(size_t)(b * 4096 + t) * 4 + j];
#pragma unroll
    for (int c = 0; c < 4; ++c) u[c] = ou[(size_t)(b * 4 + c) * 4096 + t];
    const float binv = 1.21267812518f;  // 1/sqrt(0.2^2+0.8^2)
#pragma unroll
    for (int c = 0; c < 4; ++c) {
        float s = 0.f;
#pragma unroll
        for (int j = 0; j < 4; ++j) s += wo[c * 4 + j] * oo[j];
        s *= so[c];
        a[c] = (0.2f * u[c] + 0.8f * s) * binv;
    }
    float mvec[4];
#pragma unroll
    for (int o = 0; o < 4; ++o) {
        float s = 0.f;
#pragma unroll
        for (int c = 0; c < 4; ++c) s += gw1[o * 8 + c] * u[c] + gw1[o * 8 + 4 + c] * a[c];
        mvec[o] = mp_silu_f(s * s1[o]);
    }
    float g0 = 0.f, g1 = 0.f;
#pragma unroll
    for (int o = 0; o < 4; ++o) { g0 += gw2[o] * mvec[o]; g1 += gw2[4 + o] * mvec[o]; }
    g0 *= s2[0]; g1 *= s2[1];
    float mx = fmaxf(g0, g1);
    float e0 = expf(g0 - mx), e1 = expf(g1 - mx);
    float invd = 1.f / (e0 + e1);
    g0 = e0 * invd; g1 = e1 * invd;
#pragma unroll
    for (int c = 0; c < 4; ++c)
        out[(size_t)(b * 4 + c) * 4096 + t] = g0 * u[c] + g1 * a[c];
}

// ---------------------------------------------------------------------------
extern "C" void kernel_launch(void* const* d_in, const int* in_sizes, int n_in,
                              void* d_out, int out_size, void* d_ws, size_t ws_size,
                              hipStream_t stream) {
    (void)in_sizes; (void)n_in; (void)out_size; (void)ws_size;

    const float* x        = (const float*)d_in[0];
    const float* time_vec = (const float*)d_in[1];
    const float* text_emb = (const float*)d_in[2];
    const float* zeta     = (const float*)d_in[5];
    const float* f_freq   = (const float*)d_in[6];
    const float* f_phase  = (const float*)d_in[7];
    const float* w_f1     = (const float*)d_in[8];
    const float* w_f2     = (const float*)d_in[9];
    const float* w_scale  = (const float*)d_in[10];
    const float* w_ru     = (const float*)d_in[11];
    const float* w_rv     = (const float*)d_in[12];
    const float* uw_in    = (const float*)d_in[13];
    const float* uw_time  = (const float*)d_in[14];
    const float* uw_mid   = (const float*)d_in[15];
    const float* uw_out   = (const float*)d_in[16];
    const float* vw_patch = (const float*)d_in[17];
    const float* v_pos    = (const float*)d_in[18];
    const float* vw_qkv   = (const float*)d_in[19];
    const float* vw_proj  = (const float*)d_in[20];
    const float* vw_time  = (const float*)d_in[21];
    const float* vw_text  = (const float*)d_in[22];
    const float* vw_mlp1  = (const float*)d_in[23];
    const float* vw_mlp2  = (const float*)d_in[24];
    const float* vw_unp   = (const float*)d_in[25];
    const float* ca_wq    = (const float*)d_in[26];
    const float* ca_wk    = (const float*)d_in[27];
    const float* ca_wv    = (const float*)d_in[28];
    const float* ca_wo    = (const float*)d_in[29];
    const float* gw1      = (const float*)d_in[30];
    const float* gw2      = (const float*)d_in[31];

    float* out = (float*)d_out;

    float* Wp = (float*)d_ws;
    size_t off = 0;
    auto alloc = [&](size_t n) { float* p = Wp + off; off += (n + 3) & ~(size_t)3; return p; };

    float* s_wf1   = alloc(1024);
    float* s_wf2   = alloc(512);
    float* s_wsc   = alloc(2);
    float* s_wru   = alloc(4);
    float* s_wrv   = alloc(4);
    float* s_uwin  = alloc(768);
    float* s_uwt   = alloc(768);
    float* s_uwm   = alloc(768);
    float* s_uwo   = alloc(16);
    float* s_vwp   = alloc(2048);
    float* s_vwqkv = alloc(6144);
    float* s_vwpr  = alloc(2048);
    float* s_vwti  = alloc(2048);
    float* s_vwte  = alloc(2048);
    float* s_vwm1  = alloc(8192);
    float* s_vwm2  = alloc(2048);
    float* s_vwun  = alloc(1024);
    float* s_cawq  = alloc(4);
    float* s_cawk  = alloc(4);
    float* s_cawv  = alloc(4);
    float* s_cawo  = alloc(4);
    float* s_gw1   = alloc(4);
    float* s_gw2   = alloc(2);

    float* femb    = alloc(1024);
    float* h1      = alloc(4096);
    float* temb    = alloc(2048);
    float* scale2  = alloc(8);
    float* mean_x  = alloc(16);
    int*   eidx    = (int*)alloc(8);
    float* gain    = alloc(8);
    float* rwv     = alloc(16);
    float* textp   = alloc(3072);
    float* tvec    = alloc(3072);      // [4b][4e*192]
    unsigned short* patchtok = (unsigned short*)alloc(32768);  // [4,64,256] bf16
    float* in_unet = alloc(65536);
    float* in_vit  = alloc(65536);
    float* out_unet= alloc(65536);
    float* out_vit = alloc(65536);
    float* vcond   = alloc(8192);      // [4b][4e*512]
    unsigned short* wtmid = (unsigned short*)alloc(663552);    // [4e][9][192][192] bf16

    // union region: UNet slot buffers alias the ViT intermediates (stream order
    // fully serializes UNet convs before the ViT stack -> aliasing safe).
    float* region  = alloc(6291456);
    unsigned short* bufA = (unsigned short*)region;                  // [8][64][64][192] bf16
    unsigned short* bufB = (unsigned short*)(region + 3145728);
    unsigned short* us   = (unsigned short*)region;                  // bf16 view
    unsigned short* vtok  = us + 0;          // [4e][256][512]
    unsigned short* vqkv  = us + 524288;     // [4e][256][1536]
    unsigned short* vao   = us + 2097152;    // [4e][256][512]
    unsigned short* vtok2 = us + 2621440;    // [4e][256][512]
    unsigned short* vhid  = us + 3145728;    // [4e][256][2048]
    unsigned short* vtok3 = us + 5242880;    // [4e][256][512]
    unsigned short* vout  = us + 5767168;    // [4e][256][256]

    float* caq     = alloc(65536);
    float* cak     = alloc(65536);
    float* cav     = alloc(65536);
    float* cao     = alloc(65536);

    // ---- merged rowscale
    RsTab tab;
    int rowCounts[23] = {1024, 512, 2, 4, 4, 768, 768, 768, 16, 2048, 6144, 2048,
                         2048, 2048, 8192, 2048, 1024, 4, 4, 4, 4, 4, 2};
    const float* srcs[23] = {w_f1, w_f2, w_scale, w_ru, w_rv, uw_in, uw_time, uw_mid, uw_out,
                             vw_patch, vw_qkv, vw_proj, vw_time, vw_text, vw_mlp1, vw_mlp2,
                             vw_unp, ca_wq, ca_wk, ca_wv, ca_wo, gw1, gw2};
    float* dsts[23] = {s_wf1, s_wf2, s_wsc, s_wru, s_wrv, s_uwin, s_uwt, s_uwm, s_uwo,
                       s_vwp, s_vwqkv, s_vwpr, s_vwti, s_vwte, s_vwm1, s_vwm2,
                       s_vwun, s_cawq, s_cawk, s_cawv, s_cawo, s_gw1, s_gw2};
    int fans[23] = {256, 1024, 512, 516, 516, 36, 512, 1728, 1728, 256, 512, 512,
                    512, 768, 512, 2048, 512, 4, 4, 4, 4, 8, 4};
    int cum = 0;
    for (int i = 0; i < 23; ++i) {
        tab.e[i].w = srcs[i]; tab.e[i].o = dsts[i];
        tab.e[i].fan = fans[i]; tab.e[i].rowStart = cum;
        cum += rowCounts[i];
    }
    rowscale_all_kernel<<<dim3(cum), dim3(256), 0, stream>>>(tab);
    wmid_cvt_kernel<<<dim3((1327104 + 255) / 256), dim3(256), 0, stream>>>(uw_mid, s_uwm, wtmid);

    auto gemv = [&](int ACT, int HASRES, const float* A, const float* W2, const float* wsc,
                    const float* res, float osc, float* o, int M, int N, int K) {
        dim3 g(M * N / 4);
        if (ACT)
            gemv_kernel<1, 0><<<g, 256, 0, stream>>>(A, W2, wsc, res, osc, o, N, K);
        else if (HASRES)
            gemv_kernel<0, 1><<<g, 256, 0, stream>>>(A, W2, wsc, res, osc, o, N, K);
        else
            gemv_kernel<0, 0><<<g, 256, 0, stream>>>(A, W2, wsc, res, osc, o, N, K);
    };

    // ---- time embedding chain
    femb_kernel<<<dim3(4), dim3(256), 0, stream>>>(time_vec, f_freq, f_phase, femb);
    gemv(1, 0, femb, w_f1, s_wf1, nullptr, 1.f, h1, 4, 1024, 256);
    gemv(0, 0, h1, w_f2, s_wf2, nullptr, 1.f, temb, 4, 512, 1024);

    scale_kernel<<<dim3(1), dim3(64), 0, stream>>>(temb, w_scale, s_wsc, zeta, scale2);
    meanx_kernel<<<dim3(16), dim3(256), 0, stream>>>(x, mean_x);
    router_kernel<<<dim3(1), dim3(64), 0, stream>>>(mean_x, scale2, temb, w_ru, s_wru, w_rv, s_wrv,
                                                    zeta, eidx, gain, rwv, out + 65536);
    make_inputs_kernel<<<dim3(256), dim3(256), 0, stream>>>(x, scale2, in_vit, in_unet);
    textp_kernel<<<dim3(12), dim3(256), 0, stream>>>(text_emb, textp);
    patchify_kernel<<<dim3(256), dim3(256), 0, stream>>>(in_vit, patchtok);

    // per-expert UNet time mod: tvec [4b][4e*192]
    gemv(0, 0, temb, uw_time, s_uwt, nullptr, 1.f, tvec, 4, 768, 512);

    hipMemsetAsync(out_unet, 0, 65536 * sizeof(float), stream);

    // ---- UNet conv chain, slot-compacted
    conv_in_kernel<<<dim3(16, 24, 8), dim3(256), 0, stream>>>(
        in_unet, uw_in, s_uwin, tvec, eidx, bufA);
    conv_mid_mfma<<<dim3(32, 3, 8), dim3(256), 0, stream>>>(
        bufA, wtmid, eidx, bufB);
    conv_out_kernel<<<dim3(16, 8, 8), dim3(256), 0, stream>>>(
        bufB, uw_out, s_uwo, eidx, gain, out_unet);

    // ---- ViT cond vectors: vcond [4b][4e*512]
    gemv(0, 0, temb, vw_time, s_vwti, nullptr, 1.f, vcond, 4, 2048, 512);
    gemv(0, 1, textp, vw_text, s_vwte, vcond, 1.f, vcond, 4, 2048, 768);

    auto mlin = [&](int ACT, const unsigned short* A, int aE, const float* W2, int wE2,
                    const float* wsc, int wscE, const float* pos, int posE,
                    const float* cond, int condRow, int condE,
                    const unsigned short* res, int resE, float osc,
                    const float* gate, unsigned short* o, int outE, int M, int N, int K) {
        dim3 g(N / 64, M / 64, 4);
        if (ACT)
            mfma_linear_kernel<1><<<g, 256, 0, stream>>>(A, aE, W2, wE2, wsc, wscE, pos, posE,
                                                         cond, condRow, condE, res, resE, osc,
                                                         gate, o, outE, M, N, K);
        else
            mfma_linear_kernel<0><<<g, 256, 0, stream>>>(A, aE, W2, wE2, wsc, wscE, pos, posE,
                                                         cond, condRow, condE, res, resE, osc,
                                                         gate, o, outE, M, N, K);
    };

    // ---- ViT expert stack (bf16 activations)
    mlin(0, patchtok, 0, vw_patch, 131072, s_vwp, 512, v_pos, 32768,
         vcond, 2048, 512, nullptr, 0, 1.f, rwv, vtok, 131072, 256, 512, 256);
    mlin(0, vtok, 131072, vw_qkv, 786432, s_vwqkv, 1536, nullptr, 0,
         nullptr, 0, 0, nullptr, 0, 1.f, rwv, vqkv, 393216, 256, 1536, 512);
    vit_attn_kernel<<<dim3(128), dim3(64), 0, stream>>>(vqkv, rwv, vao);
    mlin(0, vao, 131072, vw_proj, 262144, s_vwpr, 512, nullptr, 0,
         nullptr, 0, 0, vtok, 131072, 0.70710678f, rwv, vtok2, 131072, 256, 512, 512);
    mlin(1, vtok2, 131072, vw_mlp1, 1048576, s_vwm1, 2048, nullptr, 0,
         nullptr, 0, 0, nullptr, 0, 1.f, rwv, vhid, 524288, 256, 2048, 512);
    mlin(0, vhid, 524288, vw_mlp2, 1048576, s_vwm2, 512, nullptr, 0,
         nullptr, 0, 0, vtok2, 131072, 0.70710678f, rwv, vtok3, 131072, 256, 512, 2048);
    mlin(0, vtok3, 131072, vw_unp, 131072, s_vwun, 256, nullptr, 0,
         nullptr, 0, 0, nullptr, 0, 1.f, rwv, vout, 65536, 256, 256, 512);
    unpatch_scatter_kernel<<<dim3(256), dim3(256), 0, stream>>>(vout, rwv, out_vit);

    // ---- cross attention + fused tail
    ca_qkv_kernel<<<dim3(64), dim3(256), 0, stream>>>(out_unet, out_vit, ca_wq, s_cawq,
                                                      ca_wk, s_cawk, ca_wv, s_cawv, caq, cak, cav);
    ca_attn_kernel<<<dim3(256), dim3(512), 0, stream>>>(caq, cak, cav, cao);
    ca_final_kernel<<<dim3(64), dim3(256), 0, stream>>>(cao, out_unet, ca_wo, s_cawo,
                                                        gw1, s_gw1, gw2, s_gw2, out);
}

// Round 6
// 404.198 us; speedup vs baseline: 1.3755x; 1.0354x over previous
//
#include <hip/hip_runtime.h>
#include <math.h>

// ---------------------------------------------------------------------------
// HDMOEM round 6: ca_attn v2 — 16-way key split (1 block/CU, 16 waves/CU),
// register double-buffered 4-key prefetch, folded 0.5 scale.
// Rest identical to round 5 (passing, 418 us).
// B=4, C=4, H=W=64, E=4 experts/path, TOPK=2. Router masks all-True, ignored.
// ---------------------------------------------------------------------------

#define DEV_INLINE __device__ __forceinline__

typedef __attribute__((ext_vector_type(8))) short bf16x8;
typedef __attribute__((ext_vector_type(4))) float f32x4;

DEV_INLINE float mp_silu_f(float x) { return x / ((1.f + __expf(-x)) * 0.596f); }

DEV_INLINE unsigned short f2bf(float x) {
    unsigned u = __float_as_uint(x);
    unsigned r = (u + 0x7fffu + ((u >> 16) & 1u)) >> 16;
    return (unsigned short)r;
}
DEV_INLINE float bf2f(unsigned short u) { return __uint_as_float(((unsigned)u) << 16); }
DEV_INLINE float bflo(unsigned u) { return __uint_as_float(u << 16); }
DEV_INLINE float bfhi(unsigned u) { return __uint_as_float(u & 0xffff0000u); }

// ---------------------------------------------------------------------------
struct RsEnt { const float* w; float* o; int fan; int rowStart; };
struct RsTab { RsEnt e[23]; };

__global__ void rowscale_all_kernel(RsTab t) {
    int r = blockIdx.x;
    int ti = 0;
#pragma unroll
    for (int j = 1; j < 23; ++j)
        if (r >= t.e[j].rowStart) ti = j;
    const float* p = t.e[ti].w;
    int fan = t.e[ti].fan;
    int row = r - t.e[ti].rowStart;
    p += (size_t)row * fan;
    float s = 0.f;
    for (int i = threadIdx.x; i < fan; i += 256) { float v = p[i]; s += v * v; }
    __shared__ float red[256];
    red[threadIdx.x] = s;
    __syncthreads();
    for (int st = 128; st > 0; st >>= 1) {
        if (threadIdx.x < st) red[threadIdx.x] += red[threadIdx.x + st];
        __syncthreads();
    }
    if (threadIdx.x == 0) {
        float mean = red[0] / (float)fan;
        t.e[ti].o[row] = 1.f / sqrtf((mean + 1e-8f) * (float)fan);
    }
}

// ---- mid-conv weights: [e][oc][ic][3][3] f32 -> [e][tap][oc][ic] bf16, *wsc folded
__global__ void wmid_cvt_kernel(const float* __restrict__ w, const float* __restrict__ wsc,
                                unsigned short* __restrict__ wt) {
    int i = blockIdx.x * 256 + threadIdx.x;
    if (i >= 4 * 9 * 192 * 192) return;
    int ic = i % 192;
    int t = i / 192;
    int oc = t % 192; t /= 192;
    int tap = t % 9;
    int e = t / 9;
    wt[i] = f2bf(w[(((size_t)(e * 192 + oc) * 192 + ic) * 9) + tap] * wsc[e * 192 + oc]);
}

__global__ void femb_kernel(const float* __restrict__ tv, const float* __restrict__ fr,
                            const float* __restrict__ ph, float* __restrict__ femb) {
    int i = blockIdx.x * 256 + threadIdx.x;
    if (i >= 1024) return;
    int b = i >> 8, j = i & 255;
    femb[i] = 1.41421356237f * cosf(6.28318530717958647f * (tv[b] * fr[j] + ph[j]));
}

// ---- wave-per-output GEMV for small-M linears
template <int ACT, int HASRES>
__global__ void gemv_kernel(const float* __restrict__ A, const float* __restrict__ W,
                            const float* __restrict__ wsc, const float* __restrict__ res,
                            float osc, float* __restrict__ out, int N, int K) {
    int o = blockIdx.x * 4 + (threadIdx.x >> 6);
    int lane = threadIdx.x & 63;
    int m = o / N, n = o % N;
    const float* a = A + (size_t)m * K;
    const float* w = W + (size_t)n * K;
    float s = 0.f;
    for (int k = lane; k < K; k += 64) s += a[k] * w[k];
#pragma unroll
    for (int sh = 32; sh > 0; sh >>= 1) s += __shfl_xor(s, sh);
    if (lane == 0) {
        float val = s * wsc[n];
        if (ACT) val = mp_silu_f(val);
        if (HASRES) val = (val + res[(size_t)m * N + n]) * osc;
        out[(size_t)m * N + n] = val;
    }
}

__global__ void scale_kernel(const float* __restrict__ temb, const float* __restrict__ w,
                             const float* __restrict__ wsc, const float* __restrict__ zeta,
                             float* __restrict__ scale2) {
    __shared__ float lg[8];
    int t = threadIdx.x;
    if (t < 8) {
        int b = t >> 1, o = t & 1;
        float s = 0.f;
        for (int k = 0; k < 512; ++k) s += temb[b * 512 + k] * w[o * 512 + k];
        lg[t] = s * wsc[o] / zeta[0];
    }
    __syncthreads();
    if (t < 4) {
        float a = lg[t * 2], b2 = lg[t * 2 + 1];
        float m = fmaxf(a, b2);
        float e0 = expf(a - m), e1 = expf(b2 - m);
        float inv = 2.f / (e0 + e1);
        scale2[t * 2] = e0 * inv;
        scale2[t * 2 + 1] = e1 * inv;
    }
}

__global__ void meanx_kernel(const float* __restrict__ x, float* __restrict__ mean_x) {
    int bc = blockIdx.x;
    float s = 0.f;
    for (int i = threadIdx.x; i < 4096; i += 256) s += x[bc * 4096 + i];
    __shared__ float red[256];
    red[threadIdx.x] = s;
    __syncthreads();
    for (int st = 128; st > 0; st >>= 1) {
        if (threadIdx.x < st) red[threadIdx.x] += red[threadIdx.x + st];
        __syncthreads();
    }
    if (threadIdx.x == 0) mean_x[bc] = red[0] * (1.f / 4096.f);
}

// ---- routers: probs + top2; unet side also emits slot tables (eidx, gain)
__global__ void router_kernel(const float* __restrict__ mean_x, const float* __restrict__ scale2,
                              const float* __restrict__ temb,
                              const float* __restrict__ wu, const float* __restrict__ su,
                              const float* __restrict__ wv, const float* __restrict__ sv,
                              const float* __restrict__ zeta,
                              int* __restrict__ eidx, float* __restrict__ gain,
                              float* __restrict__ rwv,
                              float* __restrict__ probs_out) {
    __shared__ float lg[2][4][4];
    int t = threadIdx.x;
    if (t < 32) {
        int r = t >> 4, b = (t >> 2) & 3, e = t & 3;
        const float* w = (r == 0) ? wu : wv;
        const float* sc = (r == 0) ? su : sv;
        float ps = scale2[b * 2 + (r == 0 ? 1 : 0)];
        float acc = 0.f;
        for (int c = 0; c < 4; ++c) acc += mean_x[b * 4 + c] * ps * w[e * 516 + c];
        for (int j = 0; j < 512; ++j) acc += temb[b * 512 + j] * w[e * 516 + 4 + j];
        lg[r][b][e] = acc * sc[e] / zeta[0];
    }
    __syncthreads();
    if (t < 8) {
        int r = t >> 2, b = t & 3;
        float p[4];
        float mx = -1e30f;
        for (int e = 0; e < 4; ++e) mx = fmaxf(mx, lg[r][b][e]);
        float sum = 0.f;
        for (int e = 0; e < 4; ++e) { p[e] = expf(lg[r][b][e] - mx); sum += p[e]; }
        for (int e = 0; e < 4; ++e) p[e] /= sum;
        int i1 = 0;
        for (int e = 1; e < 4; ++e) if (p[e] > p[i1]) i1 = e;
        int i2 = -1;
        for (int e = 0; e < 4; ++e) { if (e == i1) continue; if (i2 < 0 || p[e] > p[i2]) i2 = e; }
        float inv = 1.f / (p[i1] + p[i2]);
        if (r == 0) {
            eidx[b * 2] = i1; eidx[b * 2 + 1] = i2;
            gain[b * 2] = p[i1] * inv; gain[b * 2 + 1] = p[i2] * inv;
        } else {
            for (int e = 0; e < 4; ++e) rwv[b * 4 + e] = 0.f;
            rwv[b * 4 + i1] = p[i1] * inv;
            rwv[b * 4 + i2] = p[i2] * inv;
        }
        for (int e = 0; e < 4; ++e) probs_out[r * 16 + b * 4 + e] = p[e];
    }
}

__global__ void make_inputs_kernel(const float* __restrict__ x, const float* __restrict__ scale2,
                                   float* __restrict__ in_vit, float* __restrict__ in_unet) {
    int i = blockIdx.x * 256 + threadIdx.x;
    if (i >= 65536) return;
    int b = i >> 14;
    float v = x[i];
    in_vit[i] = scale2[b * 2] * v;
    in_unet[i] = scale2[b * 2 + 1] * v;
}

__global__ void textp_kernel(const float* __restrict__ te, float* __restrict__ tp) {
    int i = blockIdx.x * 256 + threadIdx.x;
    if (i >= 3072) return;
    int b = i / 768, f = i % 768;
    float s = 0.f;
    for (int t = 0; t < 77; ++t) s += te[(size_t)(b * 77 + t) * 768 + f];
    tp[i] = s * (1.f / 77.f);
}

// ---- patchify -> bf16 tokens [B,64,256]
__global__ void patchify_kernel(const float* __restrict__ in_vit, unsigned short* __restrict__ pt) {
    int i = blockIdx.x * 256 + threadIdx.x;
    if (i >= 65536) return;
    int b = i >> 14;
    int r = i & 16383;
    int s = r >> 8, f = r & 255;
    int c = f >> 6, py = (f >> 3) & 7, px = f & 7;
    int gy = s >> 3, gx = s & 7;
    pt[i] = f2bf(in_vit[((b * 4 + c) * 64 + gy * 8 + py) * 64 + gx * 8 + px]);
}

// ---------------------------------------------------------------------------
// conv_in (slots): NCHW f32 -> NHWC bf16 per slot. grid (16,24,8)
__global__ void conv_in_kernel(const float* __restrict__ in, const float* __restrict__ wbase,
                               const float* __restrict__ wscb, const float* __restrict__ tvec,
                               const int* __restrict__ eidx,
                               unsigned short* __restrict__ out) {
    int z = blockIdx.z, b = z >> 1;
    int e = eidx[z];
    const float* w = wbase + (size_t)e * 6912;
    const float* wsc = wscb + e * 192;
    const float* tmod = tvec + b * 768 + e * 192;
    int tileIdx = blockIdx.x;
    int ty0 = (tileIdx >> 2) * 16, tx0 = (tileIdx & 3) * 16;
    int oc0 = blockIdx.y * 8;
    int lty = threadIdx.x >> 4, ltx = threadIdx.x & 15;
    int y = ty0 + lty, x = tx0 + ltx;
    __shared__ float tile[4][18][18];
    for (int i = threadIdx.x; i < 4 * 18 * 18; i += 256) {
        int ic = i / 324, rr = (i / 18) % 18, cc = i % 18;
        int gy = ty0 - 1 + rr, gx = tx0 - 1 + cc;
        float v = 0.f;
        if (gy >= 0 && gy < 64 && gx >= 0 && gx < 64)
            v = in[((b * 4 + ic) * 64 + gy) * 64 + gx];
        tile[ic][rr][cc] = v;
    }
    __syncthreads();
    float win[4][9];
#pragma unroll
    for (int ic = 0; ic < 4; ++ic)
#pragma unroll
        for (int ky = 0; ky < 3; ++ky)
#pragma unroll
            for (int kx = 0; kx < 3; ++kx)
                win[ic][ky * 3 + kx] = tile[ic][lty + ky][ltx + kx];
#pragma unroll
    for (int o = 0; o < 8; ++o) {
        int oc = oc0 + o;
        float acc = 0.f;
#pragma unroll
        for (int ic = 0; ic < 4; ++ic) {
            const float* wp = w + (size_t)(oc * 4 + ic) * 9;
#pragma unroll
            for (int kk = 0; kk < 9; ++kk) acc += wp[kk] * win[ic][kk];
        }
        float val = acc * wsc[oc] * (1.f + tmod[oc]);
        val = mp_silu_f(val);
        out[((z * 64 + y) * 64 + x) * 192 + oc] = f2bf(val);
    }
}

// ---------------------------------------------------------------------------
// mid conv (slots): implicit-GEMM bf16 MFMA, scale folded in wt. grid (32,3,8)
__global__ __launch_bounds__(256) void conv_mid_mfma(
    const unsigned short* __restrict__ in, const unsigned short* __restrict__ wtbase,
    const int* __restrict__ eidx,
    unsigned short* __restrict__ out) {
    int z = blockIdx.z;
    int e = eidx[z];
    const unsigned short* wt = wtbase + (size_t)e * 331776;
    int y0 = blockIdx.x * 2;
    int oc0 = blockIdx.y * 64;
    int wid = threadIdx.x >> 6, lane = threadIdx.x & 63;
    int wm = wid >> 1, wn = wid & 1;
    int l15 = lane & 15, lq = lane >> 4;

    __shared__ unsigned short Alds[4 * 66 * 40];
    f32x4 acc[4][2];
#pragma unroll
    for (int g = 0; g < 4; ++g)
#pragma unroll
        for (int f = 0; f < 2; ++f) acc[g][f] = (f32x4){0.f, 0.f, 0.f, 0.f};

    for (int icc = 0; icc < 6; ++icc) {
        int ic0 = icc * 32;
        for (int i = threadIdx.x; i < 1056; i += 256) {
            int q = i & 3;
            int xx = (i >> 2) % 66;
            int r = (i >> 2) / 66;
            int y = y0 - 1 + r, xg = xx - 1;
            uint4 val = {0u, 0u, 0u, 0u};
            if (y >= 0 && y < 64 && xg >= 0 && xg < 64)
                val = *(const uint4*)&in[((z * 64 + y) * 64 + xg) * 192 + ic0 + q * 8];
            *(uint4*)&Alds[(r * 66 + xx) * 40 + q * 8] = val;
        }
        __syncthreads();
#pragma unroll
        for (int tap = 0; tap < 9; ++tap) {
            int ky = tap / 3, kx = tap % 3;
            bf16x8 bfr[2];
#pragma unroll
            for (int fn = 0; fn < 2; ++fn) {
                int oc = oc0 + wn * 32 + fn * 16 + l15;
                bfr[fn] = *(const bf16x8*)&wt[(size_t)(tap * 192 + oc) * 192 + ic0 + 8 * lq];
            }
            int r = wm + ky;
#pragma unroll
            for (int g = 0; g < 4; ++g) {
                int xx = g * 16 + l15 + kx;
                bf16x8 afr = *(const bf16x8*)&Alds[(r * 66 + xx) * 40 + 8 * lq];
                acc[g][0] = __builtin_amdgcn_mfma_f32_16x16x32_bf16(afr, bfr[0], acc[g][0], 0, 0, 0);
                acc[g][1] = __builtin_amdgcn_mfma_f32_16x16x32_bf16(afr, bfr[1], acc[g][1], 0, 0, 0);
            }
        }
        __syncthreads();
    }
    int orow = y0 + wm;
#pragma unroll
    for (int g = 0; g < 4; ++g)
#pragma unroll
        for (int fn = 0; fn < 2; ++fn) {
            int oc = oc0 + wn * 32 + fn * 16 + l15;
#pragma unroll
            for (int r2 = 0; r2 < 4; ++r2) {
                int px = g * 16 + lq * 4 + r2;
                float v = mp_silu_f(acc[g][fn][r2]);
                out[((z * 64 + orow) * 64 + px) * 192 + oc] = f2bf(v);
            }
        }
}

// ---------------------------------------------------------------------------
// conv_out (slots, split-K): grid (16 tiles, 8 kchunks, 8 slots), atomicAdd.
__global__ __launch_bounds__(256) void conv_out_kernel(
    const unsigned short* __restrict__ in, const float* __restrict__ wbase,
    const float* __restrict__ wscb, const int* __restrict__ eidx,
    const float* __restrict__ gain, float* __restrict__ out) {
    int z = blockIdx.z, b = z >> 1;
    int e = eidx[z];
    float g = gain[z];
    const float* w = wbase + (size_t)e * 6912;
    const float* wsc = wscb + e * 4;
    int c0 = blockIdx.y * 24;
    int tileIdx = blockIdx.x;
    int ty0 = (tileIdx >> 2) * 16, tx0 = (tileIdx & 3) * 16;
    int lty = threadIdx.x >> 4, ltx = threadIdx.x & 15;
    int y = ty0 + lty, x = tx0 + ltx;
    __shared__ float tile[24][18][18];
    for (int i = threadIdx.x; i < 972; i += 256) {
        int q = i % 3, cell = i / 3;
        int rr = cell / 18, cc = cell % 18;
        int gy = ty0 - 1 + rr, gx = tx0 - 1 + cc;
        uint4 raw = {0u, 0u, 0u, 0u};
        if (gy >= 0 && gy < 64 && gx >= 0 && gx < 64)
            raw = *(const uint4*)&in[((z * 64 + gy) * 64 + gx) * 192 + c0 + q * 8];
        int icb = q * 8;
        tile[icb + 0][rr][cc] = bflo(raw.x);
        tile[icb + 1][rr][cc] = bfhi(raw.x);
        tile[icb + 2][rr][cc] = bflo(raw.y);
        tile[icb + 3][rr][cc] = bfhi(raw.y);
        tile[icb + 4][rr][cc] = bflo(raw.z);
        tile[icb + 5][rr][cc] = bfhi(raw.z);
        tile[icb + 6][rr][cc] = bflo(raw.w);
        tile[icb + 7][rr][cc] = bfhi(raw.w);
    }
    __syncthreads();
    float acc[4] = {0.f, 0.f, 0.f, 0.f};
#pragma unroll
    for (int ic = 0; ic < 24; ++ic) {
        float win[9];
#pragma unroll
        for (int ky = 0; ky < 3; ++ky)
#pragma unroll
            for (int kx = 0; kx < 3; ++kx)
                win[ky * 3 + kx] = tile[ic][lty + ky][ltx + kx];
#pragma unroll
        for (int o = 0; o < 4; ++o) {
            const float* wp = w + (size_t)(o * 192 + c0 + ic) * 9;
#pragma unroll
            for (int kk = 0; kk < 9; ++kk) acc[o] += wp[kk] * win[kk];
        }
    }
#pragma unroll
    for (int o = 0; o < 4; ++o)
        atomicAdd(&out[((b * 4 + o) * 64 + y) * 64 + x], g * acc[o] * wsc[o]);
}

// ---------------------------------------------------------------------------
// bf16 MFMA linear v3: A bf16 [M,K], W f32 [N,K] (converted on stage), software
// pipelined. BM=64, BN=64, 4 waves 2x2 of 32x32. grid (N/64, M/64, E).
template <int ACT>
__global__ __launch_bounds__(256) void mfma_linear_kernel(
    const unsigned short* __restrict__ A, int aE,
    const float* __restrict__ W, int wE,
    const float* __restrict__ wsc, int wscE,
    const float* __restrict__ pos, int posE,
    const float* __restrict__ cond, int condRow, int condE,
    const unsigned short* __restrict__ res, int resE, float outscale,
    const float* __restrict__ gate,
    unsigned short* __restrict__ outp, int outE,
    int M, int N, int K) {
    int e = blockIdx.z;
    int bm = blockIdx.y * 64, bn = blockIdx.x * 64;
    if (gate && gate[(bm >> 6) * 4 + e] == 0.f) return;
    A += (size_t)e * aE;
    W += (size_t)e * wE;
    wsc += (size_t)e * wscE;
    if (pos) pos += (size_t)e * posE;
    if (cond) cond += (size_t)e * condE;
    if (res) res += (size_t)e * resE;
    outp += (size_t)e * outE;

    int tid = threadIdx.x;
    int wid = tid >> 6, lane = tid & 63;
    int wm = wid >> 1, wn = wid & 1;
    int l15 = lane & 15, lq = lane >> 4;
    __shared__ unsigned short Al[64 * 72];
    __shared__ unsigned short Wl[64 * 72];
    f32x4 acc[2][2];
#pragma unroll
    for (int mf = 0; mf < 2; ++mf)
#pragma unroll
        for (int nf = 0; nf < 2; ++nf) acc[mf][nf] = (f32x4){0.f, 0.f, 0.f, 0.f};

    int ar = tid >> 3, ac = (tid & 7) * 8;
    int wr = tid >> 4, wc = (tid & 15) * 4;
    uint4 pa0, pa1;
    float4 pw0, pw1, pw2, pw3;

    auto gload = [&](int k0) {
        pa0 = *(const uint4*)&A[(size_t)(bm + ar) * K + k0 + ac];
        pa1 = *(const uint4*)&A[(size_t)(bm + ar + 32) * K + k0 + ac];
        pw0 = *(const float4*)&W[(size_t)(bn + wr) * K + k0 + wc];
        pw1 = *(const float4*)&W[(size_t)(bn + wr + 16) * K + k0 + wc];
        pw2 = *(const float4*)&W[(size_t)(bn + wr + 32) * K + k0 + wc];
        pw3 = *(const float4*)&W[(size_t)(bn + wr + 48) * K + k0 + wc];
    };
    auto sstore = [&]() {
        *(uint4*)&Al[ar * 72 + ac] = pa0;
        *(uint4*)&Al[(ar + 32) * 72 + ac] = pa1;
        ushort4 s;
        s.x = f2bf(pw0.x); s.y = f2bf(pw0.y); s.z = f2bf(pw0.z); s.w = f2bf(pw0.w);
        *(ushort4*)&Wl[wr * 72 + wc] = s;
        s.x = f2bf(pw1.x); s.y = f2bf(pw1.y); s.z = f2bf(pw1.z); s.w = f2bf(pw1.w);
        *(ushort4*)&Wl[(wr + 16) * 72 + wc] = s;
        s.x = f2bf(pw2.x); s.y = f2bf(pw2.y); s.z = f2bf(pw2.z); s.w = f2bf(pw2.w);
        *(ushort4*)&Wl[(wr + 32) * 72 + wc] = s;
        s.x = f2bf(pw3.x); s.y = f2bf(pw3.y); s.z = f2bf(pw3.z); s.w = f2bf(pw3.w);
        *(ushort4*)&Wl[(wr + 48) * 72 + wc] = s;
    };

    int nk = K >> 6;
    gload(0);
    for (int kk = 0; kk < nk; ++kk) {
        sstore();
        __syncthreads();
        if (kk + 1 < nk) gload((kk + 1) << 6);
#pragma unroll
        for (int ks = 0; ks < 2; ++ks) {
            bf16x8 af[2], wf[2];
#pragma unroll
            for (int mf = 0; mf < 2; ++mf)
                af[mf] = *(const bf16x8*)&Al[(wm * 32 + mf * 16 + l15) * 72 + ks * 32 + lq * 8];
#pragma unroll
            for (int nf = 0; nf < 2; ++nf)
                wf[nf] = *(const bf16x8*)&Wl[(wn * 32 + nf * 16 + l15) * 72 + ks * 32 + lq * 8];
#pragma unroll
            for (int mf = 0; mf < 2; ++mf)
#pragma unroll
                for (int nf = 0; nf < 2; ++nf)
                    acc[mf][nf] = __builtin_amdgcn_mfma_f32_16x16x32_bf16(af[mf], wf[nf], acc[mf][nf], 0, 0, 0);
        }
        __syncthreads();
    }
#pragma unroll
    for (int mf = 0; mf < 2; ++mf)
#pragma unroll
        for (int nf = 0; nf < 2; ++nf) {
            int n = bn + wn * 32 + nf * 16 + l15;
            float ws = wsc[n];
#pragma unroll
            for (int r = 0; r < 4; ++r) {
                int m = bm + wm * 32 + mf * 16 + lq * 4 + r;
                float val = acc[mf][nf][r] * ws;
                if (pos) val += pos[(m & 63) * N + n];
                if (cond) val *= (1.f + cond[(m >> 6) * condRow + n]);
                if (ACT) val = mp_silu_f(val);
                if (res) val = (val + bf2f(res[(size_t)m * N + n])) * outscale;
                outp[(size_t)m * N + n] = f2bf(val);
            }
        }
}

// ---- ViT self-attention over (e,b,h); bf16 IO, vectorized loads
__global__ void vit_attn_kernel(const unsigned short* __restrict__ qkv_base,
                                const float* __restrict__ rwv,
                                unsigned short* __restrict__ out_base) {
    int e = blockIdx.x >> 5, b = (blockIdx.x >> 3) & 3, h = blockIdx.x & 7;
    if (rwv[b * 4 + e] == 0.f) return;
    const unsigned short* qkv = qkv_base + (size_t)e * 393216;
    unsigned short* out = out_base + (size_t)e * 131072;
    __shared__ float ks[64][68], vs[64][68], sc[64][65];
    int tid = threadIdx.x;
    for (int i = tid; i < 512; i += 64) {
        int j = i >> 3, c = (i & 7) * 8;
        const unsigned short* kp = &qkv[(size_t)(b * 64 + j) * 1536 + 512 + h * 64 + c];
        uint4 kr = *(const uint4*)kp;
        uint4 vr = *(const uint4*)(kp + 512);
        float* kd = &ks[j][c];
        float* vd = &vs[j][c];
        kd[0] = bflo(kr.x); kd[1] = bfhi(kr.x); kd[2] = bflo(kr.y); kd[3] = bfhi(kr.y);
        kd[4] = bflo(kr.z); kd[5] = bfhi(kr.z); kd[6] = bflo(kr.w); kd[7] = bfhi(kr.w);
        vd[0] = bflo(vr.x); vd[1] = bfhi(vr.x); vd[2] = bflo(vr.y); vd[3] = bfhi(vr.y);
        vd[4] = bflo(vr.z); vd[5] = bfhi(vr.z); vd[6] = bflo(vr.w); vd[7] = bfhi(vr.w);
    }
    float qreg[64];
#pragma unroll
    for (int c8 = 0; c8 < 8; ++c8) {
        uint4 qr = *(const uint4*)&qkv[(size_t)(b * 64 + tid) * 1536 + h * 64 + c8 * 8];
        qreg[c8 * 8 + 0] = bflo(qr.x); qreg[c8 * 8 + 1] = bfhi(qr.x);
        qreg[c8 * 8 + 2] = bflo(qr.y); qreg[c8 * 8 + 3] = bfhi(qr.y);
        qreg[c8 * 8 + 4] = bflo(qr.z); qreg[c8 * 8 + 5] = bfhi(qr.z);
        qreg[c8 * 8 + 6] = bflo(qr.w); qreg[c8 * 8 + 7] = bfhi(qr.w);
    }
    __syncthreads();
    float mx = -1e30f;
    for (int j = 0; j < 64; ++j) {
        float s = 0.f;
#pragma unroll
        for (int d4 = 0; d4 < 16; ++d4) {
            float4 kk = *(const float4*)&ks[j][d4 * 4];
            s += qreg[d4 * 4] * kk.x + qreg[d4 * 4 + 1] * kk.y +
                 qreg[d4 * 4 + 2] * kk.z + qreg[d4 * 4 + 3] * kk.w;
        }
        s *= 0.125f;
        sc[tid][j] = s;
        mx = fmaxf(mx, s);
    }
    float sum = 0.f;
    for (int j = 0; j < 64; ++j) { float ee = __expf(sc[tid][j] - mx); sc[tid][j] = ee; sum += ee; }
    float inv = 1.f / sum;
    float4 acc4[16];
#pragma unroll
    for (int d4 = 0; d4 < 16; ++d4) acc4[d4] = (float4){0.f, 0.f, 0.f, 0.f};
    for (int j = 0; j < 64; ++j) {
        float ee = sc[tid][j];
#pragma unroll
        for (int d4 = 0; d4 < 16; ++d4) {
            float4 vv = *(const float4*)&vs[j][d4 * 4];
            acc4[d4].x += ee * vv.x; acc4[d4].y += ee * vv.y;
            acc4[d4].z += ee * vv.z; acc4[d4].w += ee * vv.w;
        }
    }
    unsigned short* op = &out[(size_t)(b * 64 + tid) * 512 + h * 64];
#pragma unroll
    for (int d4 = 0; d4 < 16; ++d4) {
        ushort4 r;
        r.x = f2bf(acc4[d4].x * inv); r.y = f2bf(acc4[d4].y * inv);
        r.z = f2bf(acc4[d4].z * inv); r.w = f2bf(acc4[d4].w * inv);
        *(ushort4*)&op[d4 * 4] = r;
    }
}

__global__ void unpatch_scatter_kernel(const unsigned short* __restrict__ vout,
                                       const float* __restrict__ rwv,
                                       float* __restrict__ out_vit) {
    int i = blockIdx.x * 256 + threadIdx.x;
    if (i >= 65536) return;
    int b = i >> 14;
    int c = (i >> 12) & 3, y = (i >> 6) & 63, x = i & 63;
    int f = c * 64 + (y & 7) * 8 + (x & 7);
    int s = (y >> 3) * 8 + (x >> 3);
    int idx = (b * 64 + s) * 256 + f;
    float acc = 0.f;
#pragma unroll
    for (int e = 0; e < 4; ++e) {
        float g = rwv[b * 4 + e];
        if (g != 0.f) acc += g * bf2f(vout[e * 65536 + idx]);
    }
    out_vit[i] = acc;
}

__global__ void ca_qkv_kernel(const float* __restrict__ ou, const float* __restrict__ ov,
                              const float* __restrict__ wq, const float* __restrict__ sq,
                              const float* __restrict__ wk, const float* __restrict__ sk,
                              const float* __restrict__ wv, const float* __restrict__ sv,
                              float* __restrict__ q, float* __restrict__ kx, float* __restrict__ vx) {
    int i = blockIdx.x * 256 + threadIdx.x;
    if (i >= 16384) return;
    int b = i >> 12, t = i & 4095;
    float u[4], c[4];
#pragma unroll
    for (int cc = 0; cc < 4; ++cc) {
        u[cc] = ou[(size_t)(b * 4 + cc) * 4096 + t];
        c[cc] = ov[(size_t)(b * 4 + cc) * 4096 + t];
    }
#pragma unroll
    for (int o = 0; o < 4; ++o) {
        float aq = 0.f, ak = 0.f, av = 0.f;
#pragma unroll
        for (int cc = 0; cc < 4; ++cc) {
            aq += wq[o * 4 + cc] * u[cc];
            ak += wk[o * 4 + cc] * c[cc];
            av += wv[o * 4 + cc] * c[cc];
        }
        q[(size_t)(b * 4096 + t) * 4 + o] = aq * sq[o];
        kx[(size_t)(b * 4096 + t) * 4 + o] = ak * sk[o];
        vx[(size_t)(b * 4096 + t) * 4 + o] = av * sv[o];
    }
}

// ---- cross-attn v2: 16 key-segments (1024 threads), reg-prefetched 4-key
// blocks, LDS merge. grid 256 blocks (1/CU), 0.5 scale folded into q.
__global__ __launch_bounds__(1024) void ca_attn_kernel(
    const float* __restrict__ q, const float* __restrict__ k,
    const float* __restrict__ v, float* __restrict__ o) {
    int b = blockIdx.x >> 6;                 // 64 qgroups of 64 per batch
    int qg = blockIdx.x & 63;
    int lq = threadIdx.x & 63, seg = threadIdx.x >> 6;   // seg 0..15
    int qt = qg * 64 + lq;
    float4 qv = *(const float4*)&q[(size_t)(b * 4096 + qt) * 4];
    qv.x *= 0.5f; qv.y *= 0.5f; qv.z *= 0.5f; qv.w *= 0.5f;   // 1/sqrt(E=4)
    const float4* kb = (const float4*)(k + (size_t)b * 16384);
    const float4* vb = (const float4*)(v + (size_t)b * 16384);
    float m = -1e30f, l = 0.f, a0 = 0.f, a1 = 0.f, a2 = 0.f, a3 = 0.f;
    int j0 = seg * 256;

    float4 k0[4], v0[4], k1[4], v1[4];
    auto loadkv = [&](int j, float4* kk, float4* vv) {
#pragma unroll
        for (int u = 0; u < 4; ++u) { kk[u] = kb[j + u]; vv[u] = vb[j + u]; }
    };
    auto process = [&](const float4* kk, const float4* vv) {
        float s[4];
#pragma unroll
        for (int u = 0; u < 4; ++u) {
            float4 kx2 = kk[u];
            s[u] = qv.x * kx2.x + qv.y * kx2.y + qv.z * kx2.z + qv.w * kx2.w;
        }
        float bm = fmaxf(fmaxf(s[0], s[1]), fmaxf(s[2], s[3]));
        float nm = fmaxf(m, bm);
        float corr = __expf(m - nm);
        l *= corr; a0 *= corr; a1 *= corr; a2 *= corr; a3 *= corr;
#pragma unroll
        for (int u = 0; u < 4; ++u) {
            float ee = __expf(s[u] - nm);
            float4 vv2 = vv[u];
            l += ee;
            a0 += ee * vv2.x; a1 += ee * vv2.y; a2 += ee * vv2.z; a3 += ee * vv2.w;
        }
        m = nm;
    };

    loadkv(j0, k0, v0);
    for (int j = j0; j < j0 + 256; j += 8) {
        loadkv(j + 4, k1, v1);
        process(k0, v0);
        if (j + 8 < j0 + 256) loadkv(j + 8, k0, v0);
        process(k1, v1);
    }

    __shared__ float red[16][64][6];
    red[seg][lq][0] = m; red[seg][lq][1] = l;
    red[seg][lq][2] = a0; red[seg][lq][3] = a1;
    red[seg][lq][4] = a2; red[seg][lq][5] = a3;
    __syncthreads();
    if (threadIdx.x < 64) {
        int qq = threadIdx.x;
        float mm = -1e30f, ll = 0.f, b0 = 0.f, b1 = 0.f, b2 = 0.f, b3 = 0.f;
#pragma unroll
        for (int s2 = 0; s2 < 16; ++s2) {
            float m2 = red[s2][qq][0], l2 = red[s2][qq][1];
            float nm = fmaxf(mm, m2);
            float c1 = __expf(mm - nm), c2 = __expf(m2 - nm);
            ll = ll * c1 + l2 * c2;
            b0 = b0 * c1 + red[s2][qq][2] * c2;
            b1 = b1 * c1 + red[s2][qq][3] * c2;
            b2 = b2 * c1 + red[s2][qq][4] * c2;
            b3 = b3 * c1 + red[s2][qq][5] * c2;
            mm = nm;
        }
        float inv = 1.f / ll;
        float* op = &o[(size_t)(b * 4096 + qg * 64 + qq) * 4];
        op[0] = b0 * inv; op[1] = b1 * inv; op[2] = b2 * inv; op[3] = b3 * inv;
    }
}

// ---- fused: out-proj + balanced blend + gated combine -> d_out
__global__ void ca_final_kernel(const float* __restrict__ ao, const float* __restrict__ ou,
                                const float* __restrict__ wo, const float* __restrict__ so,
                                const float* __restrict__ gw1, const float* __restrict__ s1,
                                const float* __restrict__ gw2, const float* __restrict__ s2,
                                float* __restrict__ out) {
    int i = blockIdx.x * 256 + threadIdx.x;
    if (i >= 16384) return;
    int b = i >> 12, t = i & 4095;
    float oo[4], u[4], a[4];
#pragma unroll
    for (int j = 0; j < 4; ++j) oo[j] = ao[(size_t)(b * 4096 + t) * 4 + j];
#pragma unroll
    for (int c = 0; c < 4; ++c) u[c] = ou[(size_t)(b * 4 + c) * 4096 + t];
    const float binv = 1.21267812518f;  // 1/sqrt(0.2^2+0.8^2)
#pragma unroll
    for (int c = 0; c < 4; ++c) {
        float s = 0.f;
#pragma unroll
        for (int j = 0; j < 4; ++j) s += wo[c * 4 + j] * oo[j];
        s *= so[c];
        a[c] = (0.2f * u[c] + 0.8f * s) * binv;
    }
    float mvec[4];
#pragma unroll
    for (int o = 0; o < 4; ++o) {
        float s = 0.f;
#pragma unroll
        for (int c = 0; c < 4; ++c) s += gw1[o * 8 + c] * u[c] + gw1[o * 8 + 4 + c] * a[c];
        mvec[o] = mp_silu_f(s * s1[o]);
    }
    float g0 = 0.f, g1 = 0.f;
#pragma unroll
    for (int o = 0; o < 4; ++o) { g0 += gw2[o] * mvec[o]; g1 += gw2[4 + o] * mvec[o]; }
    g0 *= s2[0]; g1 *= s2[1];
    float mx = fmaxf(g0, g1);
    float e0 = expf(g0 - mx), e1 = expf(g1 - mx);
    float invd = 1.f / (e0 + e1);
    g0 = e0 * invd; g1 = e1 * invd;
#pragma unroll
    for (int c = 0; c < 4; ++c)
        out[(size_t)(b * 4 + c) * 4096 + t] = g0 * u[c] + g1 * a[c];
}

// ---------------------------------------------------------------------------
extern "C" void kernel_launch(void* const* d_in, const int* in_sizes, int n_in,
                              void* d_out, int out_size, void* d_ws, size_t ws_size,
                              hipStream_t stream) {
    (void)in_sizes; (void)n_in; (void)out_size; (void)ws_size;

    const float* x        = (const float*)d_in[0];
    const float* time_vec = (const float*)d_in[1];
    const float* text_emb = (const float*)d_in[2];
    const float* zeta     = (const float*)d_in[5];
    const float* f_freq   = (const float*)d_in[6];
    const float* f_phase  = (const float*)d_in[7];
    const float* w_f1     = (const float*)d_in[8];
    const float* w_f2     = (const float*)d_in[9];
    const float* w_scale  = (const float*)d_in[10];
    const float* w_ru     = (const float*)d_in[11];
    const float* w_rv     = (const float*)d_in[12];
    const float* uw_in    = (const float*)d_in[13];
    const float* uw_time  = (const float*)d_in[14];
    const float* uw_mid   = (const float*)d_in[15];
    const float* uw_out   = (const float*)d_in[16];
    const float* vw_patch = (const float*)d_in[17];
    const float* v_pos    = (const float*)d_in[18];
    const float* vw_qkv   = (const float*)d_in[19];
    const float* vw_proj  = (const float*)d_in[20];
    const float* vw_time  = (const float*)d_in[21];
    const float* vw_text  = (const float*)d_in[22];
    const float* vw_mlp1  = (const float*)d_in[23];
    const float* vw_mlp2  = (const float*)d_in[24];
    const float* vw_unp   = (const float*)d_in[25];
    const float* ca_wq    = (const float*)d_in[26];
    const float* ca_wk    = (const float*)d_in[27];
    const float* ca_wv    = (const float*)d_in[28];
    const float* ca_wo    = (const float*)d_in[29];
    const float* gw1      = (const float*)d_in[30];
    const float* gw2      = (const float*)d_in[31];

    float* out = (float*)d_out;

    float* Wp = (float*)d_ws;
    size_t off = 0;
    auto alloc = [&](size_t n) { float* p = Wp + off; off += (n + 3) & ~(size_t)3; return p; };

    float* s_wf1   = alloc(1024);
    float* s_wf2   = alloc(512);
    float* s_wsc   = alloc(2);
    float* s_wru   = alloc(4);
    float* s_wrv   = alloc(4);
    float* s_uwin  = alloc(768);
    float* s_uwt   = alloc(768);
    float* s_uwm   = alloc(768);
    float* s_uwo   = alloc(16);
    float* s_vwp   = alloc(2048);
    float* s_vwqkv = alloc(6144);
    float* s_vwpr  = alloc(2048);
    float* s_vwti  = alloc(2048);
    float* s_vwte  = alloc(2048);
    float* s_vwm1  = alloc(8192);
    float* s_vwm2  = alloc(2048);
    float* s_vwun  = alloc(1024);
    float* s_cawq  = alloc(4);
    float* s_cawk  = alloc(4);
    float* s_cawv  = alloc(4);
    float* s_cawo  = alloc(4);
    float* s_gw1   = alloc(4);
    float* s_gw2   = alloc(2);

    float* femb    = alloc(1024);
    float* h1      = alloc(4096);
    float* temb    = alloc(2048);
    float* scale2  = alloc(8);
    float* mean_x  = alloc(16);
    int*   eidx    = (int*)alloc(8);
    float* gain    = alloc(8);
    float* rwv     = alloc(16);
    float* textp   = alloc(3072);
    float* tvec    = alloc(3072);      // [4b][4e*192]
    unsigned short* patchtok = (unsigned short*)alloc(32768);  // [4,64,256] bf16
    float* in_unet = alloc(65536);
    float* in_vit  = alloc(65536);
    float* out_unet= alloc(65536);
    float* out_vit = alloc(65536);
    float* vcond   = alloc(8192);      // [4b][4e*512]
    unsigned short* wtmid = (unsigned short*)alloc(663552);    // [4e][9][192][192] bf16

    // union region: UNet slot buffers alias the ViT intermediates (stream order
    // fully serializes UNet convs before the ViT stack -> aliasing safe).
    float* region  = alloc(6291456);
    unsigned short* bufA = (unsigned short*)region;                  // [8][64][64][192] bf16
    unsigned short* bufB = (unsigned short*)(region + 3145728);
    unsigned short* us   = (unsigned short*)region;                  // bf16 view
    unsigned short* vtok  = us + 0;          // [4e][256][512]
    unsigned short* vqkv  = us + 524288;     // [4e][256][1536]
    unsigned short* vao   = us + 2097152;    // [4e][256][512]
    unsigned short* vtok2 = us + 2621440;    // [4e][256][512]
    unsigned short* vhid  = us + 3145728;    // [4e][256][2048]
    unsigned short* vtok3 = us + 5242880;    // [4e][256][512]
    unsigned short* vout  = us + 5767168;    // [4e][256][256]

    float* caq     = alloc(65536);
    float* cak     = alloc(65536);
    float* cav     = alloc(65536);
    float* cao     = alloc(65536);

    // ---- merged rowscale
    RsTab tab;
    int rowCounts[23] = {1024, 512, 2, 4, 4, 768, 768, 768, 16, 2048, 6144, 2048,
                         2048, 2048, 8192, 2048, 1024, 4, 4, 4, 4, 4, 2};
    const float* srcs[23] = {w_f1, w_f2, w_scale, w_ru, w_rv, uw_in, uw_time, uw_mid, uw_out,
                             vw_patch, vw_qkv, vw_proj, vw_time, vw_text, vw_mlp1, vw_mlp2,
                             vw_unp, ca_wq, ca_wk, ca_wv, ca_wo, gw1, gw2};
    float* dsts[23] = {s_wf1, s_wf2, s_wsc, s_wru, s_wrv, s_uwin, s_uwt, s_uwm, s_uwo,
                       s_vwp, s_vwqkv, s_vwpr, s_vwti, s_vwte, s_vwm1, s_vwm2,
                       s_vwun, s_cawq, s_cawk, s_cawv, s_cawo, s_gw1, s_gw2};
    int fans[23] = {256, 1024, 512, 516, 516, 36, 512, 1728, 1728, 256, 512, 512,
                    512, 768, 512, 2048, 512, 4, 4, 4, 4, 8, 4};
    int cum = 0;
    for (int i = 0; i < 23; ++i) {
        tab.e[i].w = srcs[i]; tab.e[i].o = dsts[i];
        tab.e[i].fan = fans[i]; tab.e[i].rowStart = cum;
        cum += rowCounts[i];
    }
    rowscale_all_kernel<<<dim3(cum), dim3(256), 0, stream>>>(tab);
    wmid_cvt_kernel<<<dim3((1327104 + 255) / 256), dim3(256), 0, stream>>>(uw_mid, s_uwm, wtmid);

    auto gemv = [&](int ACT, int HASRES, const float* A, const float* W2, const float* wsc,
                    const float* res, float osc, float* o, int M, int N, int K) {
        dim3 g(M * N / 4);
        if (ACT)
            gemv_kernel<1, 0><<<g, 256, 0, stream>>>(A, W2, wsc, res, osc, o, N, K);
        else if (HASRES)
            gemv_kernel<0, 1><<<g, 256, 0, stream>>>(A, W2, wsc, res, osc, o, N, K);
        else
            gemv_kernel<0, 0><<<g, 256, 0, stream>>>(A, W2, wsc, res, osc, o, N, K);
    };

    // ---- time embedding chain
    femb_kernel<<<dim3(4), dim3(256), 0, stream>>>(time_vec, f_freq, f_phase, femb);
    gemv(1, 0, femb, w_f1, s_wf1, nullptr, 1.f, h1, 4, 1024, 256);
    gemv(0, 0, h1, w_f2, s_wf2, nullptr, 1.f, temb, 4, 512, 1024);

    scale_kernel<<<dim3(1), dim3(64), 0, stream>>>(temb, w_scale, s_wsc, zeta, scale2);
    meanx_kernel<<<dim3(16), dim3(256), 0, stream>>>(x, mean_x);
    router_kernel<<<dim3(1), dim3(64), 0, stream>>>(mean_x, scale2, temb, w_ru, s_wru, w_rv, s_wrv,
                                                    zeta, eidx, gain, rwv, out + 65536);
    make_inputs_kernel<<<dim3(256), dim3(256), 0, stream>>>(x, scale2, in_vit, in_unet);
    textp_kernel<<<dim3(12), dim3(256), 0, stream>>>(text_emb, textp);
    patchify_kernel<<<dim3(256), dim3(256), 0, stream>>>(in_vit, patchtok);

    // per-expert UNet time mod: tvec [4b][4e*192]
    gemv(0, 0, temb, uw_time, s_uwt, nullptr, 1.f, tvec, 4, 768, 512);

    hipMemsetAsync(out_unet, 0, 65536 * sizeof(float), stream);

    // ---- UNet conv chain, slot-compacted
    conv_in_kernel<<<dim3(16, 24, 8), dim3(256), 0, stream>>>(
        in_unet, uw_in, s_uwin, tvec, eidx, bufA);
    conv_mid_mfma<<<dim3(32, 3, 8), dim3(256), 0, stream>>>(
        bufA, wtmid, eidx, bufB);
    conv_out_kernel<<<dim3(16, 8, 8), dim3(256), 0, stream>>>(
        bufB, uw_out, s_uwo, eidx, gain, out_unet);

    // ---- ViT cond vectors: vcond [4b][4e*512]
    gemv(0, 0, temb, vw_time, s_vwti, nullptr, 1.f, vcond, 4, 2048, 512);
    gemv(0, 1, textp, vw_text, s_vwte, vcond, 1.f, vcond, 4, 2048, 768);

    auto mlin = [&](int ACT, const unsigned short* A, int aE, const float* W2, int wE2,
                    const float* wsc, int wscE, const float* pos, int posE,
                    const float* cond, int condRow, int condE,
                    const unsigned short* res, int resE, float osc,
                    const float* gate, unsigned short* o, int outE, int M, int N, int K) {
        dim3 g(N / 64, M / 64, 4);
        if (ACT)
            mfma_linear_kernel<1><<<g, 256, 0, stream>>>(A, aE, W2, wE2, wsc, wscE, pos, posE,
                                                         cond, condRow, condE, res, resE, osc,
                                                         gate, o, outE, M, N, K);
        else
            mfma_linear_kernel<0><<<g, 256, 0, stream>>>(A, aE, W2, wE2, wsc, wscE, pos, posE,
                                                         cond, condRow, condE, res, resE, osc,
                                                         gate, o, outE, M, N, K);
    };

    // ---- ViT expert stack (bf16 activations)
    mlin(0, patchtok, 0, vw_patch, 131072, s_vwp, 512, v_pos, 32768,
         vcond, 2048, 512, nullptr, 0, 1.f, rwv, vtok, 131072, 256, 512, 256);
    mlin(0, vtok, 131072, vw_qkv, 786432, s_vwqkv, 1536, nullptr, 0,
         nullptr, 0, 0, nullptr, 0, 1.f, rwv, vqkv, 393216, 256, 1536, 512);
    vit_attn_kernel<<<dim3(128), dim3(64), 0, stream>>>(vqkv, rwv, vao);
    mlin(0, vao, 131072, vw_proj, 262144, s_vwpr, 512, nullptr, 0,
         nullptr, 0, 0, vtok, 131072, 0.70710678f, rwv, vtok2, 131072, 256, 512, 512);
    mlin(1, vtok2, 131072, vw_mlp1, 1048576, s_vwm1, 2048, nullptr, 0,
         nullptr, 0, 0, nullptr, 0, 1.f, rwv, vhid, 524288, 256, 2048, 512);
    mlin(0, vhid, 524288, vw_mlp2, 1048576, s_vwm2, 512, nullptr, 0,
         nullptr, 0, 0, vtok2, 131072, 0.70710678f, rwv, vtok3, 131072, 256, 512, 2048);
    mlin(0, vtok3, 131072, vw_unp, 131072, s_vwun, 256, nullptr, 0,
         nullptr, 0, 0, nullptr, 0, 1.f, rwv, vout, 65536, 256, 256, 512);
    unpatch_scatter_kernel<<<dim3(256), dim3(256), 0, stream>>>(vout, rwv, out_vit);

    // ---- cross attention + fused tail
    ca_qkv_kernel<<<dim3(64), dim3(256), 0, stream>>>(out_unet, out_vit, ca_wq, s_cawq,
                                                      ca_wk, s_cawk, ca_wv, s_cawv, caq, cak, cav);
    ca_attn_kernel<<<dim3(256), dim3(1024), 0, stream>>>(caq, cak, cav, cao);
    ca_final_kernel<<<dim3(64), dim3(256), 0, stream>>>(cao, out_unet, ca_wo, s_cawo,
                                                        gw1, s_gw1, gw2, s_gw2, out);
}

// Round 7
// 364.663 us; speedup vs baseline: 1.5246x; 1.1084x over previous
//
#include <hip/hip_runtime.h>
#include <math.h>

// ---------------------------------------------------------------------------
// HDMOEM round 7: vit_attn v2 (4 waves/block, 4-lane-per-query shfl merge),
// ca_attn v3 (dual-stream online softmax + defer-correction).
// Rest identical to round 6 (passing, 404 us).
// B=4, C=4, H=W=64, E=4 experts/path, TOPK=2. Router masks all-True, ignored.
// ---------------------------------------------------------------------------

#define DEV_INLINE __device__ __forceinline__

typedef __attribute__((ext_vector_type(8))) short bf16x8;
typedef __attribute__((ext_vector_type(4))) float f32x4;

DEV_INLINE float mp_silu_f(float x) { return x / ((1.f + __expf(-x)) * 0.596f); }

DEV_INLINE unsigned short f2bf(float x) {
    unsigned u = __float_as_uint(x);
    unsigned r = (u + 0x7fffu + ((u >> 16) & 1u)) >> 16;
    return (unsigned short)r;
}
DEV_INLINE float bf2f(unsigned short u) { return __uint_as_float(((unsigned)u) << 16); }
DEV_INLINE float bflo(unsigned u) { return __uint_as_float(u << 16); }
DEV_INLINE float bfhi(unsigned u) { return __uint_as_float(u & 0xffff0000u); }

// ---------------------------------------------------------------------------
struct RsEnt { const float* w; float* o; int fan; int rowStart; };
struct RsTab { RsEnt e[23]; };

__global__ void rowscale_all_kernel(RsTab t) {
    int r = blockIdx.x;
    int ti = 0;
#pragma unroll
    for (int j = 1; j < 23; ++j)
        if (r >= t.e[j].rowStart) ti = j;
    const float* p = t.e[ti].w;
    int fan = t.e[ti].fan;
    int row = r - t.e[ti].rowStart;
    p += (size_t)row * fan;
    float s = 0.f;
    for (int i = threadIdx.x; i < fan; i += 256) { float v = p[i]; s += v * v; }
    __shared__ float red[256];
    red[threadIdx.x] = s;
    __syncthreads();
    for (int st = 128; st > 0; st >>= 1) {
        if (threadIdx.x < st) red[threadIdx.x] += red[threadIdx.x + st];
        __syncthreads();
    }
    if (threadIdx.x == 0) {
        float mean = red[0] / (float)fan;
        t.e[ti].o[row] = 1.f / sqrtf((mean + 1e-8f) * (float)fan);
    }
}

// ---- mid-conv weights: [e][oc][ic][3][3] f32 -> [e][tap][oc][ic] bf16, *wsc folded
__global__ void wmid_cvt_kernel(const float* __restrict__ w, const float* __restrict__ wsc,
                                unsigned short* __restrict__ wt) {
    int i = blockIdx.x * 256 + threadIdx.x;
    if (i >= 4 * 9 * 192 * 192) return;
    int ic = i % 192;
    int t = i / 192;
    int oc = t % 192; t /= 192;
    int tap = t % 9;
    int e = t / 9;
    wt[i] = f2bf(w[(((size_t)(e * 192 + oc) * 192 + ic) * 9) + tap] * wsc[e * 192 + oc]);
}

__global__ void femb_kernel(const float* __restrict__ tv, const float* __restrict__ fr,
                            const float* __restrict__ ph, float* __restrict__ femb) {
    int i = blockIdx.x * 256 + threadIdx.x;
    if (i >= 1024) return;
    int b = i >> 8, j = i & 255;
    femb[i] = 1.41421356237f * cosf(6.28318530717958647f * (tv[b] * fr[j] + ph[j]));
}

// ---- wave-per-output GEMV for small-M linears
template <int ACT, int HASRES>
__global__ void gemv_kernel(const float* __restrict__ A, const float* __restrict__ W,
                            const float* __restrict__ wsc, const float* __restrict__ res,
                            float osc, float* __restrict__ out, int N, int K) {
    int o = blockIdx.x * 4 + (threadIdx.x >> 6);
    int lane = threadIdx.x & 63;
    int m = o / N, n = o % N;
    const float* a = A + (size_t)m * K;
    const float* w = W + (size_t)n * K;
    float s = 0.f;
    for (int k = lane; k < K; k += 64) s += a[k] * w[k];
#pragma unroll
    for (int sh = 32; sh > 0; sh >>= 1) s += __shfl_xor(s, sh);
    if (lane == 0) {
        float val = s * wsc[n];
        if (ACT) val = mp_silu_f(val);
        if (HASRES) val = (val + res[(size_t)m * N + n]) * osc;
        out[(size_t)m * N + n] = val;
    }
}

__global__ void scale_kernel(const float* __restrict__ temb, const float* __restrict__ w,
                             const float* __restrict__ wsc, const float* __restrict__ zeta,
                             float* __restrict__ scale2) {
    __shared__ float lg[8];
    int t = threadIdx.x;
    if (t < 8) {
        int b = t >> 1, o = t & 1;
        float s = 0.f;
        for (int k = 0; k < 512; ++k) s += temb[b * 512 + k] * w[o * 512 + k];
        lg[t] = s * wsc[o] / zeta[0];
    }
    __syncthreads();
    if (t < 4) {
        float a = lg[t * 2], b2 = lg[t * 2 + 1];
        float m = fmaxf(a, b2);
        float e0 = expf(a - m), e1 = expf(b2 - m);
        float inv = 2.f / (e0 + e1);
        scale2[t * 2] = e0 * inv;
        scale2[t * 2 + 1] = e1 * inv;
    }
}

__global__ void meanx_kernel(const float* __restrict__ x, float* __restrict__ mean_x) {
    int bc = blockIdx.x;
    float s = 0.f;
    for (int i = threadIdx.x; i < 4096; i += 256) s += x[bc * 4096 + i];
    __shared__ float red[256];
    red[threadIdx.x] = s;
    __syncthreads();
    for (int st = 128; st > 0; st >>= 1) {
        if (threadIdx.x < st) red[threadIdx.x] += red[threadIdx.x + st];
        __syncthreads();
    }
    if (threadIdx.x == 0) mean_x[bc] = red[0] * (1.f / 4096.f);
}

// ---- routers: probs + top2; unet side also emits slot tables (eidx, gain)
__global__ void router_kernel(const float* __restrict__ mean_x, const float* __restrict__ scale2,
                              const float* __restrict__ temb,
                              const float* __restrict__ wu, const float* __restrict__ su,
                              const float* __restrict__ wv, const float* __restrict__ sv,
                              const float* __restrict__ zeta,
                              int* __restrict__ eidx, float* __restrict__ gain,
                              float* __restrict__ rwv,
                              float* __restrict__ probs_out) {
    __shared__ float lg[2][4][4];
    int t = threadIdx.x;
    if (t < 32) {
        int r = t >> 4, b = (t >> 2) & 3, e = t & 3;
        const float* w = (r == 0) ? wu : wv;
        const float* sc = (r == 0) ? su : sv;
        float ps = scale2[b * 2 + (r == 0 ? 1 : 0)];
        float acc = 0.f;
        for (int c = 0; c < 4; ++c) acc += mean_x[b * 4 + c] * ps * w[e * 516 + c];
        for (int j = 0; j < 512; ++j) acc += temb[b * 512 + j] * w[e * 516 + 4 + j];
        lg[r][b][e] = acc * sc[e] / zeta[0];
    }
    __syncthreads();
    if (t < 8) {
        int r = t >> 2, b = t & 3;
        float p[4];
        float mx = -1e30f;
        for (int e = 0; e < 4; ++e) mx = fmaxf(mx, lg[r][b][e]);
        float sum = 0.f;
        for (int e = 0; e < 4; ++e) { p[e] = expf(lg[r][b][e] - mx); sum += p[e]; }
        for (int e = 0; e < 4; ++e) p[e] /= sum;
        int i1 = 0;
        for (int e = 1; e < 4; ++e) if (p[e] > p[i1]) i1 = e;
        int i2 = -1;
        for (int e = 0; e < 4; ++e) { if (e == i1) continue; if (i2 < 0 || p[e] > p[i2]) i2 = e; }
        float inv = 1.f / (p[i1] + p[i2]);
        if (r == 0) {
            eidx[b * 2] = i1; eidx[b * 2 + 1] = i2;
            gain[b * 2] = p[i1] * inv; gain[b * 2 + 1] = p[i2] * inv;
        } else {
            for (int e = 0; e < 4; ++e) rwv[b * 4 + e] = 0.f;
            rwv[b * 4 + i1] = p[i1] * inv;
            rwv[b * 4 + i2] = p[i2] * inv;
        }
        for (int e = 0; e < 4; ++e) probs_out[r * 16 + b * 4 + e] = p[e];
    }
}

__global__ void make_inputs_kernel(const float* __restrict__ x, const float* __restrict__ scale2,
                                   float* __restrict__ in_vit, float* __restrict__ in_unet) {
    int i = blockIdx.x * 256 + threadIdx.x;
    if (i >= 65536) return;
    int b = i >> 14;
    float v = x[i];
    in_vit[i] = scale2[b * 2] * v;
    in_unet[i] = scale2[b * 2 + 1] * v;
}

__global__ void textp_kernel(const float* __restrict__ te, float* __restrict__ tp) {
    int i = blockIdx.x * 256 + threadIdx.x;
    if (i >= 3072) return;
    int b = i / 768, f = i % 768;
    float s = 0.f;
    for (int t = 0; t < 77; ++t) s += te[(size_t)(b * 77 + t) * 768 + f];
    tp[i] = s * (1.f / 77.f);
}

// ---- patchify -> bf16 tokens [B,64,256]
__global__ void patchify_kernel(const float* __restrict__ in_vit, unsigned short* __restrict__ pt) {
    int i = blockIdx.x * 256 + threadIdx.x;
    if (i >= 65536) return;
    int b = i >> 14;
    int r = i & 16383;
    int s = r >> 8, f = r & 255;
    int c = f >> 6, py = (f >> 3) & 7, px = f & 7;
    int gy = s >> 3, gx = s & 7;
    pt[i] = f2bf(in_vit[((b * 4 + c) * 64 + gy * 8 + py) * 64 + gx * 8 + px]);
}

// ---------------------------------------------------------------------------
// conv_in (slots): NCHW f32 -> NHWC bf16 per slot. grid (16,24,8)
__global__ void conv_in_kernel(const float* __restrict__ in, const float* __restrict__ wbase,
                               const float* __restrict__ wscb, const float* __restrict__ tvec,
                               const int* __restrict__ eidx,
                               unsigned short* __restrict__ out) {
    int z = blockIdx.z, b = z >> 1;
    int e = eidx[z];
    const float* w = wbase + (size_t)e * 6912;
    const float* wsc = wscb + e * 192;
    const float* tmod = tvec + b * 768 + e * 192;
    int tileIdx = blockIdx.x;
    int ty0 = (tileIdx >> 2) * 16, tx0 = (tileIdx & 3) * 16;
    int oc0 = blockIdx.y * 8;
    int lty = threadIdx.x >> 4, ltx = threadIdx.x & 15;
    int y = ty0 + lty, x = tx0 + ltx;
    __shared__ float tile[4][18][18];
    for (int i = threadIdx.x; i < 4 * 18 * 18; i += 256) {
        int ic = i / 324, rr = (i / 18) % 18, cc = i % 18;
        int gy = ty0 - 1 + rr, gx = tx0 - 1 + cc;
        float v = 0.f;
        if (gy >= 0 && gy < 64 && gx >= 0 && gx < 64)
            v = in[((b * 4 + ic) * 64 + gy) * 64 + gx];
        tile[ic][rr][cc] = v;
    }
    __syncthreads();
    float win[4][9];
#pragma unroll
    for (int ic = 0; ic < 4; ++ic)
#pragma unroll
        for (int ky = 0; ky < 3; ++ky)
#pragma unroll
            for (int kx = 0; kx < 3; ++kx)
                win[ic][ky * 3 + kx] = tile[ic][lty + ky][ltx + kx];
#pragma unroll
    for (int o = 0; o < 8; ++o) {
        int oc = oc0 + o;
        float acc = 0.f;
#pragma unroll
        for (int ic = 0; ic < 4; ++ic) {
            const float* wp = w + (size_t)(oc * 4 + ic) * 9;
#pragma unroll
            for (int kk = 0; kk < 9; ++kk) acc += wp[kk] * win[ic][kk];
        }
        float val = acc * wsc[oc] * (1.f + tmod[oc]);
        val = mp_silu_f(val);
        out[((z * 64 + y) * 64 + x) * 192 + oc] = f2bf(val);
    }
}

// ---------------------------------------------------------------------------
// mid conv (slots): implicit-GEMM bf16 MFMA, scale folded in wt. grid (32,3,8)
__global__ __launch_bounds__(256) void conv_mid_mfma(
    const unsigned short* __restrict__ in, const unsigned short* __restrict__ wtbase,
    const int* __restrict__ eidx,
    unsigned short* __restrict__ out) {
    int z = blockIdx.z;
    int e = eidx[z];
    const unsigned short* wt = wtbase + (size_t)e * 331776;
    int y0 = blockIdx.x * 2;
    int oc0 = blockIdx.y * 64;
    int wid = threadIdx.x >> 6, lane = threadIdx.x & 63;
    int wm = wid >> 1, wn = wid & 1;
    int l15 = lane & 15, lq = lane >> 4;

    __shared__ unsigned short Alds[4 * 66 * 40];
    f32x4 acc[4][2];
#pragma unroll
    for (int g = 0; g < 4; ++g)
#pragma unroll
        for (int f = 0; f < 2; ++f) acc[g][f] = (f32x4){0.f, 0.f, 0.f, 0.f};

    for (int icc = 0; icc < 6; ++icc) {
        int ic0 = icc * 32;
        for (int i = threadIdx.x; i < 1056; i += 256) {
            int q = i & 3;
            int xx = (i >> 2) % 66;
            int r = (i >> 2) / 66;
            int y = y0 - 1 + r, xg = xx - 1;
            uint4 val = {0u, 0u, 0u, 0u};
            if (y >= 0 && y < 64 && xg >= 0 && xg < 64)
                val = *(const uint4*)&in[((z * 64 + y) * 64 + xg) * 192 + ic0 + q * 8];
            *(uint4*)&Alds[(r * 66 + xx) * 40 + q * 8] = val;
        }
        __syncthreads();
#pragma unroll
        for (int tap = 0; tap < 9; ++tap) {
            int ky = tap / 3, kx = tap % 3;
            bf16x8 bfr[2];
#pragma unroll
            for (int fn = 0; fn < 2; ++fn) {
                int oc = oc0 + wn * 32 + fn * 16 + l15;
                bfr[fn] = *(const bf16x8*)&wt[(size_t)(tap * 192 + oc) * 192 + ic0 + 8 * lq];
            }
            int r = wm + ky;
#pragma unroll
            for (int g = 0; g < 4; ++g) {
                int xx = g * 16 + l15 + kx;
                bf16x8 afr = *(const bf16x8*)&Alds[(r * 66 + xx) * 40 + 8 * lq];
                acc[g][0] = __builtin_amdgcn_mfma_f32_16x16x32_bf16(afr, bfr[0], acc[g][0], 0, 0, 0);
                acc[g][1] = __builtin_amdgcn_mfma_f32_16x16x32_bf16(afr, bfr[1], acc[g][1], 0, 0, 0);
            }
        }
        __syncthreads();
    }
    int orow = y0 + wm;
#pragma unroll
    for (int g = 0; g < 4; ++g)
#pragma unroll
        for (int fn = 0; fn < 2; ++fn) {
            int oc = oc0 + wn * 32 + fn * 16 + l15;
#pragma unroll
            for (int r2 = 0; r2 < 4; ++r2) {
                int px = g * 16 + lq * 4 + r2;
                float v = mp_silu_f(acc[g][fn][r2]);
                out[((z * 64 + orow) * 64 + px) * 192 + oc] = f2bf(v);
            }
        }
}

// ---------------------------------------------------------------------------
// conv_out (slots, split-K): grid (16 tiles, 8 kchunks, 8 slots), atomicAdd.
__global__ __launch_bounds__(256) void conv_out_kernel(
    const unsigned short* __restrict__ in, const float* __restrict__ wbase,
    const float* __restrict__ wscb, const int* __restrict__ eidx,
    const float* __restrict__ gain, float* __restrict__ out) {
    int z = blockIdx.z, b = z >> 1;
    int e = eidx[z];
    float g = gain[z];
    const float* w = wbase + (size_t)e * 6912;
    const float* wsc = wscb + e * 4;
    int c0 = blockIdx.y * 24;
    int tileIdx = blockIdx.x;
    int ty0 = (tileIdx >> 2) * 16, tx0 = (tileIdx & 3) * 16;
    int lty = threadIdx.x >> 4, ltx = threadIdx.x & 15;
    int y = ty0 + lty, x = tx0 + ltx;
    __shared__ float tile[24][18][18];
    for (int i = threadIdx.x; i < 972; i += 256) {
        int q = i % 3, cell = i / 3;
        int rr = cell / 18, cc = cell % 18;
        int gy = ty0 - 1 + rr, gx = tx0 - 1 + cc;
        uint4 raw = {0u, 0u, 0u, 0u};
        if (gy >= 0 && gy < 64 && gx >= 0 && gx < 64)
            raw = *(const uint4*)&in[((z * 64 + gy) * 64 + gx) * 192 + c0 + q * 8];
        int icb = q * 8;
        tile[icb + 0][rr][cc] = bflo(raw.x);
        tile[icb + 1][rr][cc] = bfhi(raw.x);
        tile[icb + 2][rr][cc] = bflo(raw.y);
        tile[icb + 3][rr][cc] = bfhi(raw.y);
        tile[icb + 4][rr][cc] = bflo(raw.z);
        tile[icb + 5][rr][cc] = bfhi(raw.z);
        tile[icb + 6][rr][cc] = bflo(raw.w);
        tile[icb + 7][rr][cc] = bfhi(raw.w);
    }
    __syncthreads();
    float acc[4] = {0.f, 0.f, 0.f, 0.f};
#pragma unroll
    for (int ic = 0; ic < 24; ++ic) {
        float win[9];
#pragma unroll
        for (int ky = 0; ky < 3; ++ky)
#pragma unroll
            for (int kx = 0; kx < 3; ++kx)
                win[ky * 3 + kx] = tile[ic][lty + ky][ltx + kx];
#pragma unroll
        for (int o = 0; o < 4; ++o) {
            const float* wp = w + (size_t)(o * 192 + c0 + ic) * 9;
#pragma unroll
            for (int kk = 0; kk < 9; ++kk) acc[o] += wp[kk] * win[kk];
        }
    }
#pragma unroll
    for (int o = 0; o < 4; ++o)
        atomicAdd(&out[((b * 4 + o) * 64 + y) * 64 + x], g * acc[o] * wsc[o]);
}

// ---------------------------------------------------------------------------
// bf16 MFMA linear v3: A bf16 [M,K], W f32 [N,K] (converted on stage), software
// pipelined. BM=64, BN=64, 4 waves 2x2 of 32x32. grid (N/64, M/64, E).
template <int ACT>
__global__ __launch_bounds__(256) void mfma_linear_kernel(
    const unsigned short* __restrict__ A, int aE,
    const float* __restrict__ W, int wE,
    const float* __restrict__ wsc, int wscE,
    const float* __restrict__ pos, int posE,
    const float* __restrict__ cond, int condRow, int condE,
    const unsigned short* __restrict__ res, int resE, float outscale,
    const float* __restrict__ gate,
    unsigned short* __restrict__ outp, int outE,
    int M, int N, int K) {
    int e = blockIdx.z;
    int bm = blockIdx.y * 64, bn = blockIdx.x * 64;
    if (gate && gate[(bm >> 6) * 4 + e] == 0.f) return;
    A += (size_t)e * aE;
    W += (size_t)e * wE;
    wsc += (size_t)e * wscE;
    if (pos) pos += (size_t)e * posE;
    if (cond) cond += (size_t)e * condE;
    if (res) res += (size_t)e * resE;
    outp += (size_t)e * outE;

    int tid = threadIdx.x;
    int wid = tid >> 6, lane = tid & 63;
    int wm = wid >> 1, wn = wid & 1;
    int l15 = lane & 15, lq = lane >> 4;
    __shared__ unsigned short Al[64 * 72];
    __shared__ unsigned short Wl[64 * 72];
    f32x4 acc[2][2];
#pragma unroll
    for (int mf = 0; mf < 2; ++mf)
#pragma unroll
        for (int nf = 0; nf < 2; ++nf) acc[mf][nf] = (f32x4){0.f, 0.f, 0.f, 0.f};

    int ar = tid >> 3, ac = (tid & 7) * 8;
    int wr = tid >> 4, wc = (tid & 15) * 4;
    uint4 pa0, pa1;
    float4 pw0, pw1, pw2, pw3;

    auto gload = [&](int k0) {
        pa0 = *(const uint4*)&A[(size_t)(bm + ar) * K + k0 + ac];
        pa1 = *(const uint4*)&A[(size_t)(bm + ar + 32) * K + k0 + ac];
        pw0 = *(const float4*)&W[(size_t)(bn + wr) * K + k0 + wc];
        pw1 = *(const float4*)&W[(size_t)(bn + wr + 16) * K + k0 + wc];
        pw2 = *(const float4*)&W[(size_t)(bn + wr + 32) * K + k0 + wc];
        pw3 = *(const float4*)&W[(size_t)(bn + wr + 48) * K + k0 + wc];
    };
    auto sstore = [&]() {
        *(uint4*)&Al[ar * 72 + ac] = pa0;
        *(uint4*)&Al[(ar + 32) * 72 + ac] = pa1;
        ushort4 s;
        s.x = f2bf(pw0.x); s.y = f2bf(pw0.y); s.z = f2bf(pw0.z); s.w = f2bf(pw0.w);
        *(ushort4*)&Wl[wr * 72 + wc] = s;
        s.x = f2bf(pw1.x); s.y = f2bf(pw1.y); s.z = f2bf(pw1.z); s.w = f2bf(pw1.w);
        *(ushort4*)&Wl[(wr + 16) * 72 + wc] = s;
        s.x = f2bf(pw2.x); s.y = f2bf(pw2.y); s.z = f2bf(pw2.z); s.w = f2bf(pw2.w);
        *(ushort4*)&Wl[(wr + 32) * 72 + wc] = s;
        s.x = f2bf(pw3.x); s.y = f2bf(pw3.y); s.z = f2bf(pw3.z); s.w = f2bf(pw3.w);
        *(ushort4*)&Wl[(wr + 48) * 72 + wc] = s;
    };

    int nk = K >> 6;
    gload(0);
    for (int kk = 0; kk < nk; ++kk) {
        sstore();
        __syncthreads();
        if (kk + 1 < nk) gload((kk + 1) << 6);
#pragma unroll
        for (int ks = 0; ks < 2; ++ks) {
            bf16x8 af[2], wf[2];
#pragma unroll
            for (int mf = 0; mf < 2; ++mf)
                af[mf] = *(const bf16x8*)&Al[(wm * 32 + mf * 16 + l15) * 72 + ks * 32 + lq * 8];
#pragma unroll
            for (int nf = 0; nf < 2; ++nf)
                wf[nf] = *(const bf16x8*)&Wl[(wn * 32 + nf * 16 + l15) * 72 + ks * 32 + lq * 8];
#pragma unroll
            for (int mf = 0; mf < 2; ++mf)
#pragma unroll
                for (int nf = 0; nf < 2; ++nf)
                    acc[mf][nf] = __builtin_amdgcn_mfma_f32_16x16x32_bf16(af[mf], wf[nf], acc[mf][nf], 0, 0, 0);
        }
        __syncthreads();
    }
#pragma unroll
    for (int mf = 0; mf < 2; ++mf)
#pragma unroll
        for (int nf = 0; nf < 2; ++nf) {
            int n = bn + wn * 32 + nf * 16 + l15;
            float ws = wsc[n];
#pragma unroll
            for (int r = 0; r < 4; ++r) {
                int m = bm + wm * 32 + mf * 16 + lq * 4 + r;
                float val = acc[mf][nf][r] * ws;
                if (pos) val += pos[(m & 63) * N + n];
                if (cond) val *= (1.f + cond[(m >> 6) * condRow + n]);
                if (ACT) val = mp_silu_f(val);
                if (res) val = (val + bf2f(res[(size_t)m * N + n])) * outscale;
                outp[(size_t)m * N + n] = f2bf(val);
            }
        }
}

// ---- ViT self-attention v2: 256 threads (4 waves), 4 lanes/query x 16 keys,
// shfl_xor online-softmax merge. grid 128 over (e,b,h).
__global__ __launch_bounds__(256) void vit_attn_kernel(
    const unsigned short* __restrict__ qkv_base,
    const float* __restrict__ rwv,
    unsigned short* __restrict__ out_base) {
    int e = blockIdx.x >> 5, b = (blockIdx.x >> 3) & 3, h = blockIdx.x & 7;
    if (rwv[b * 4 + e] == 0.f) return;
    const unsigned short* qkv = qkv_base + (size_t)e * 393216;
    unsigned short* out = out_base + (size_t)e * 131072;
    __shared__ float ks[64][68], vs[64][68];
    int tid = threadIdx.x;
    for (int i = tid; i < 512; i += 256) {
        int j = i >> 3, c = (i & 7) * 8;
        const unsigned short* kp = &qkv[(size_t)(b * 64 + j) * 1536 + 512 + h * 64 + c];
        uint4 kr = *(const uint4*)kp;
        uint4 vr = *(const uint4*)(kp + 512);
        float* kd = &ks[j][c];
        float* vd = &vs[j][c];
        kd[0] = bflo(kr.x); kd[1] = bfhi(kr.x); kd[2] = bflo(kr.y); kd[3] = bfhi(kr.y);
        kd[4] = bflo(kr.z); kd[5] = bfhi(kr.z); kd[6] = bflo(kr.w); kd[7] = bfhi(kr.w);
        vd[0] = bflo(vr.x); vd[1] = bfhi(vr.x); vd[2] = bflo(vr.y); vd[3] = bfhi(vr.y);
        vd[4] = bflo(vr.z); vd[5] = bfhi(vr.z); vd[6] = bflo(vr.w); vd[7] = bfhi(vr.w);
    }
    int qr = tid >> 2, kq = tid & 3;     // query row, key quarter
    float qreg[64];
#pragma unroll
    for (int c8 = 0; c8 < 8; ++c8) {
        uint4 q4 = *(const uint4*)&qkv[(size_t)(b * 64 + qr) * 1536 + h * 64 + c8 * 8];
        qreg[c8 * 8 + 0] = bflo(q4.x); qreg[c8 * 8 + 1] = bfhi(q4.x);
        qreg[c8 * 8 + 2] = bflo(q4.y); qreg[c8 * 8 + 3] = bfhi(q4.y);
        qreg[c8 * 8 + 4] = bflo(q4.z); qreg[c8 * 8 + 5] = bfhi(q4.z);
        qreg[c8 * 8 + 6] = bflo(q4.w); qreg[c8 * 8 + 7] = bfhi(q4.w);
    }
    __syncthreads();
    float sc[16];
    float m = -1e30f;
    int j0 = kq * 16;
#pragma unroll
    for (int jj = 0; jj < 16; ++jj) {
        int j = j0 + jj;
        float s = 0.f;
#pragma unroll
        for (int d4 = 0; d4 < 16; ++d4) {
            float4 kk = *(const float4*)&ks[j][d4 * 4];
            s += qreg[d4 * 4] * kk.x + qreg[d4 * 4 + 1] * kk.y +
                 qreg[d4 * 4 + 2] * kk.z + qreg[d4 * 4 + 3] * kk.w;
        }
        s *= 0.125f;
        sc[jj] = s;
        m = fmaxf(m, s);
    }
    float l = 0.f;
    float4 acc4[16];
#pragma unroll
    for (int d4 = 0; d4 < 16; ++d4) acc4[d4] = (float4){0.f, 0.f, 0.f, 0.f};
#pragma unroll
    for (int jj = 0; jj < 16; ++jj) {
        int j = j0 + jj;
        float ee = __expf(sc[jj] - m);
        l += ee;
#pragma unroll
        for (int d4 = 0; d4 < 16; ++d4) {
            float4 vv = *(const float4*)&vs[j][d4 * 4];
            acc4[d4].x += ee * vv.x; acc4[d4].y += ee * vv.y;
            acc4[d4].z += ee * vv.z; acc4[d4].w += ee * vv.w;
        }
    }
    // merge the 4 lane-partials per query (exact online-softmax merge;
    // symmetric combination -> all 4 lanes converge to identical result)
#pragma unroll
    for (int mask = 1; mask <= 2; mask <<= 1) {
        float m2 = __shfl_xor(m, mask);
        float l2 = __shfl_xor(l, mask);
        float nm = fmaxf(m, m2);
        float c1 = __expf(m - nm), c2 = __expf(m2 - nm);
        l = l * c1 + l2 * c2;
#pragma unroll
        for (int d4 = 0; d4 < 16; ++d4) {
            acc4[d4].x = acc4[d4].x * c1 + __shfl_xor(acc4[d4].x, mask) * c2;
            acc4[d4].y = acc4[d4].y * c1 + __shfl_xor(acc4[d4].y, mask) * c2;
            acc4[d4].z = acc4[d4].z * c1 + __shfl_xor(acc4[d4].z, mask) * c2;
            acc4[d4].w = acc4[d4].w * c1 + __shfl_xor(acc4[d4].w, mask) * c2;
        }
        m = nm;
    }
    float inv = 1.f / l;
    // each lane writes its own 16-d slice (all 4 lanes hold the full result)
    unsigned short* op = &out[(size_t)(b * 64 + qr) * 512 + h * 64 + kq * 16];
#pragma unroll
    for (int d4 = 0; d4 < 4; ++d4) {
        int dd = kq * 4 + d4;
        ushort4 r;
        r.x = f2bf(acc4[dd].x * inv); r.y = f2bf(acc4[dd].y * inv);
        r.z = f2bf(acc4[dd].z * inv); r.w = f2bf(acc4[dd].w * inv);
        *(ushort4*)&op[d4 * 4] = r;
    }
}

__global__ void unpatch_scatter_kernel(const unsigned short* __restrict__ vout,
                                       const float* __restrict__ rwv,
                                       float* __restrict__ out_vit) {
    int i = blockIdx.x * 256 + threadIdx.x;
    if (i >= 65536) return;
    int b = i >> 14;
    int c = (i >> 12) & 3, y = (i >> 6) & 63, x = i & 63;
    int f = c * 64 + (y & 7) * 8 + (x & 7);
    int s = (y >> 3) * 8 + (x >> 3);
    int idx = (b * 64 + s) * 256 + f;
    float acc = 0.f;
#pragma unroll
    for (int e = 0; e < 4; ++e) {
        float g = rwv[b * 4 + e];
        if (g != 0.f) acc += g * bf2f(vout[e * 65536 + idx]);
    }
    out_vit[i] = acc;
}

__global__ void ca_qkv_kernel(const float* __restrict__ ou, const float* __restrict__ ov,
                              const float* __restrict__ wq, const float* __restrict__ sq,
                              const float* __restrict__ wk, const float* __restrict__ sk,
                              const float* __restrict__ wv, const float* __restrict__ sv,
                              float* __restrict__ q, float* __restrict__ kx, float* __restrict__ vx) {
    int i = blockIdx.x * 256 + threadIdx.x;
    if (i >= 16384) return;
    int b = i >> 12, t = i & 4095;
    float u[4], c[4];
#pragma unroll
    for (int cc = 0; cc < 4; ++cc) {
        u[cc] = ou[(size_t)(b * 4 + cc) * 4096 + t];
        c[cc] = ov[(size_t)(b * 4 + cc) * 4096 + t];
    }
#pragma unroll
    for (int o = 0; o < 4; ++o) {
        float aq = 0.f, ak = 0.f, av = 0.f;
#pragma unroll
        for (int cc = 0; cc < 4; ++cc) {
            aq += wq[o * 4 + cc] * u[cc];
            ak += wk[o * 4 + cc] * c[cc];
            av += wv[o * 4 + cc] * c[cc];
        }
        q[(size_t)(b * 4096 + t) * 4 + o] = aq * sq[o];
        kx[(size_t)(b * 4096 + t) * 4 + o] = ak * sk[o];
        vx[(size_t)(b * 4096 + t) * 4 + o] = av * sv[o];
    }
}

// ---- cross-attn v3: 16 key-segments, DUAL independent online-softmax streams
// per lane + defer-correction (rescale only when batch max exceeds running m).
__global__ __launch_bounds__(1024) void ca_attn_kernel(
    const float* __restrict__ q, const float* __restrict__ k,
    const float* __restrict__ v, float* __restrict__ o) {
    int b = blockIdx.x >> 6;
    int qg = blockIdx.x & 63;
    int lq = threadIdx.x & 63, seg = threadIdx.x >> 6;   // seg 0..15
    int qt = qg * 64 + lq;
    float4 qv = *(const float4*)&q[(size_t)(b * 4096 + qt) * 4];
    qv.x *= 0.5f; qv.y *= 0.5f; qv.z *= 0.5f; qv.w *= 0.5f;   // 1/sqrt(E=4)
    const float4* kb = (const float4*)(k + (size_t)b * 16384);
    const float4* vb = (const float4*)(v + (size_t)b * 16384);
    int jA = seg * 256, jB = jA + 128;
    float mA = -1e30f, lA = 0.f, aA0 = 0.f, aA1 = 0.f, aA2 = 0.f, aA3 = 0.f;
    float mB = -1e30f, lB = 0.f, aB0 = 0.f, aB1 = 0.f, aB2 = 0.f, aB3 = 0.f;

    for (int jj = 0; jj < 128; jj += 4) {
        float4 ka[4], va[4], kc[4], vc[4];
#pragma unroll
        for (int u = 0; u < 4; ++u) {
            ka[u] = kb[jA + jj + u]; va[u] = vb[jA + jj + u];
            kc[u] = kb[jB + jj + u]; vc[u] = vb[jB + jj + u];
        }
        float sA[4], sB[4];
#pragma unroll
        for (int u = 0; u < 4; ++u) {
            sA[u] = qv.x * ka[u].x + qv.y * ka[u].y + qv.z * ka[u].z + qv.w * ka[u].w;
            sB[u] = qv.x * kc[u].x + qv.y * kc[u].y + qv.z * kc[u].z + qv.w * kc[u].w;
        }
        float bmA = fmaxf(fmaxf(sA[0], sA[1]), fmaxf(sA[2], sA[3]));
        float bmB = fmaxf(fmaxf(sB[0], sB[1]), fmaxf(sB[2], sB[3]));
        if (bmA > mA) {
            float corr = __expf(mA - bmA);
            lA *= corr; aA0 *= corr; aA1 *= corr; aA2 *= corr; aA3 *= corr;
            mA = bmA;
        }
        if (bmB > mB) {
            float corr = __expf(mB - bmB);
            lB *= corr; aB0 *= corr; aB1 *= corr; aB2 *= corr; aB3 *= corr;
            mB = bmB;
        }
#pragma unroll
        for (int u = 0; u < 4; ++u) {
            float eA = __expf(sA[u] - mA);
            lA += eA;
            aA0 += eA * va[u].x; aA1 += eA * va[u].y;
            aA2 += eA * va[u].z; aA3 += eA * va[u].w;
            float eB = __expf(sB[u] - mB);
            lB += eB;
            aB0 += eB * vc[u].x; aB1 += eB * vc[u].y;
            aB2 += eB * vc[u].z; aB3 += eB * vc[u].w;
        }
    }
    // merge stream B into A
    {
        float nm = fmaxf(mA, mB);
        float c1 = __expf(mA - nm), c2 = __expf(mB - nm);
        lA = lA * c1 + lB * c2;
        aA0 = aA0 * c1 + aB0 * c2;
        aA1 = aA1 * c1 + aB1 * c2;
        aA2 = aA2 * c1 + aB2 * c2;
        aA3 = aA3 * c1 + aB3 * c2;
        mA = nm;
    }
    __shared__ float red[16][64][6];
    red[seg][lq][0] = mA; red[seg][lq][1] = lA;
    red[seg][lq][2] = aA0; red[seg][lq][3] = aA1;
    red[seg][lq][4] = aA2; red[seg][lq][5] = aA3;
    __syncthreads();
    if (threadIdx.x < 64) {
        int qq = threadIdx.x;
        float mm = -1e30f, ll = 0.f, b0 = 0.f, b1 = 0.f, b2 = 0.f, b3 = 0.f;
#pragma unroll
        for (int s2 = 0; s2 < 16; ++s2) {
            float m2 = red[s2][qq][0], l2 = red[s2][qq][1];
            float nm = fmaxf(mm, m2);
            float c1 = __expf(mm - nm), c2 = __expf(m2 - nm);
            ll = ll * c1 + l2 * c2;
            b0 = b0 * c1 + red[s2][qq][2] * c2;
            b1 = b1 * c1 + red[s2][qq][3] * c2;
            b2 = b2 * c1 + red[s2][qq][4] * c2;
            b3 = b3 * c1 + red[s2][qq][5] * c2;
            mm = nm;
        }
        float inv = 1.f / ll;
        float* op = &o[(size_t)(b * 4096 + qg * 64 + qq) * 4];
        op[0] = b0 * inv; op[1] = b1 * inv; op[2] = b2 * inv; op[3] = b3 * inv;
    }
}

// ---- fused: out-proj + balanced blend + gated combine -> d_out
__global__ void ca_final_kernel(const float* __restrict__ ao, const float* __restrict__ ou,
                                const float* __restrict__ wo, const float* __restrict__ so,
                                const float* __restrict__ gw1, const float* __restrict__ s1,
                                const float* __restrict__ gw2, const float* __restrict__ s2,
                                float* __restrict__ out) {
    int i = blockIdx.x * 256 + threadIdx.x;
    if (i >= 16384) return;
    int b = i >> 12, t = i & 4095;
    float oo[4], u[4], a[4];
#pragma unroll
    for (int j = 0; j < 4; ++j) oo[j] = ao[(size_t)(b * 4096 + t) * 4 + j];
#pragma unroll
    for (int c = 0; c < 4; ++c) u[c] = ou[(size_t)(b * 4 + c) * 4096 + t];
    const float binv = 1.21267812518f;  // 1/sqrt(0.2^2+0.8^2)
#pragma unroll
    for (int c = 0; c < 4; ++c) {
        float s = 0.f;
#pragma unroll
        for (int j = 0; j < 4; ++j) s += wo[c * 4 + j] * oo[j];
        s *= so[c];
        a[c] = (0.2f * u[c] + 0.8f * s) * binv;
    }
    float mvec[4];
#pragma unroll
    for (int o = 0; o < 4; ++o) {
        float s = 0.f;
#pragma unroll
        for (int c = 0; c < 4; ++c) s += gw1[o * 8 + c] * u[c] + gw1[o * 8 + 4 + c] * a[c];
        mvec[o] = mp_silu_f(s * s1[o]);
    }
    float g0 = 0.f, g1 = 0.f;
#pragma unroll
    for (int o = 0; o < 4; ++o) { g0 += gw2[o] * mvec[o]; g1 += gw2[4 + o] * mvec[o]; }
    g0 *= s2[0]; g1 *= s2[1];
    float mx = fmaxf(g0, g1);
    float e0 = expf(g0 - mx), e1 = expf(g1 - mx);
    float invd = 1.f / (e0 + e1);
    g0 = e0 * invd; g1 = e1 * invd;
#pragma unroll
    for (int c = 0; c < 4; ++c)
        out[(size_t)(b * 4 + c) * 4096 + t] = g0 * u[c] + g1 * a[c];
}

// ---------------------------------------------------------------------------
extern "C" void kernel_launch(void* const* d_in, const int* in_sizes, int n_in,
                              void* d_out, int out_size, void* d_ws, size_t ws_size,
                              hipStream_t stream) {
    (void)in_sizes; (void)n_in; (void)out_size; (void)ws_size;

    const float* x        = (const float*)d_in[0];
    const float* time_vec = (const float*)d_in[1];
    const float* text_emb = (const float*)d_in[2];
    const float* zeta     = (const float*)d_in[5];
    const float* f_freq   = (const float*)d_in[6];
    const float* f_phase  = (const float*)d_in[7];
    const float* w_f1     = (const float*)d_in[8];
    const float* w_f2     = (const float*)d_in[9];
    const float* w_scale  = (const float*)d_in[10];
    const float* w_ru     = (const float*)d_in[11];
    const float* w_rv     = (const float*)d_in[12];
    const float* uw_in    = (const float*)d_in[13];
    const float* uw_time  = (const float*)d_in[14];
    const float* uw_mid   = (const float*)d_in[15];
    const float* uw_out   = (const float*)d_in[16];
    const float* vw_patch = (const float*)d_in[17];
    const float* v_pos    = (const float*)d_in[18];
    const float* vw_qkv   = (const float*)d_in[19];
    const float* vw_proj  = (const float*)d_in[20];
    const float* vw_time  = (const float*)d_in[21];
    const float* vw_text  = (const float*)d_in[22];
    const float* vw_mlp1  = (const float*)d_in[23];
    const float* vw_mlp2  = (const float*)d_in[24];
    const float* vw_unp   = (const float*)d_in[25];
    const float* ca_wq    = (const float*)d_in[26];
    const float* ca_wk    = (const float*)d_in[27];
    const float* ca_wv    = (const float*)d_in[28];
    const float* ca_wo    = (const float*)d_in[29];
    const float* gw1      = (const float*)d_in[30];
    const float* gw2      = (const float*)d_in[31];

    float* out = (float*)d_out;

    float* Wp = (float*)d_ws;
    size_t off = 0;
    auto alloc = [&](size_t n) { float* p = Wp + off; off += (n + 3) & ~(size_t)3; return p; };

    float* s_wf1   = alloc(1024);
    float* s_wf2   = alloc(512);
    float* s_wsc   = alloc(2);
    float* s_wru   = alloc(4);
    float* s_wrv   = alloc(4);
    float* s_uwin  = alloc(768);
    float* s_uwt   = alloc(768);
    float* s_uwm   = alloc(768);
    float* s_uwo   = alloc(16);
    float* s_vwp   = alloc(2048);
    float* s_vwqkv = alloc(6144);
    float* s_vwpr  = alloc(2048);
    float* s_vwti  = alloc(2048);
    float* s_vwte  = alloc(2048);
    float* s_vwm1  = alloc(8192);
    float* s_vwm2  = alloc(2048);
    float* s_vwun  = alloc(1024);
    float* s_cawq  = alloc(4);
    float* s_cawk  = alloc(4);
    float* s_cawv  = alloc(4);
    float* s_cawo  = alloc(4);
    float* s_gw1   = alloc(4);
    float* s_gw2   = alloc(2);

    float* femb    = alloc(1024);
    float* h1      = alloc(4096);
    float* temb    = alloc(2048);
    float* scale2  = alloc(8);
    float* mean_x  = alloc(16);
    int*   eidx    = (int*)alloc(8);
    float* gain    = alloc(8);
    float* rwv     = alloc(16);
    float* textp   = alloc(3072);
    float* tvec    = alloc(3072);      // [4b][4e*192]
    unsigned short* patchtok = (unsigned short*)alloc(32768);  // [4,64,256] bf16
    float* in_unet = alloc(65536);
    float* in_vit  = alloc(65536);
    float* out_unet= alloc(65536);
    float* out_vit = alloc(65536);
    float* vcond   = alloc(8192);      // [4b][4e*512]
    unsigned short* wtmid = (unsigned short*)alloc(663552);    // [4e][9][192][192] bf16

    // union region: UNet slot buffers alias the ViT intermediates (stream order
    // fully serializes UNet convs before the ViT stack -> aliasing safe).
    float* region  = alloc(6291456);
    unsigned short* bufA = (unsigned short*)region;                  // [8][64][64][192] bf16
    unsigned short* bufB = (unsigned short*)(region + 3145728);
    unsigned short* us   = (unsigned short*)region;                  // bf16 view
    unsigned short* vtok  = us + 0;          // [4e][256][512]
    unsigned short* vqkv  = us + 524288;     // [4e][256][1536]
    unsigned short* vao   = us + 2097152;    // [4e][256][512]
    unsigned short* vtok2 = us + 2621440;    // [4e][256][512]
    unsigned short* vhid  = us + 3145728;    // [4e][256][2048]
    unsigned short* vtok3 = us + 5242880;    // [4e][256][512]
    unsigned short* vout  = us + 5767168;    // [4e][256][256]

    float* caq     = alloc(65536);
    float* cak     = alloc(65536);
    float* cav     = alloc(65536);
    float* cao     = alloc(65536);

    // ---- merged rowscale
    RsTab tab;
    int rowCounts[23] = {1024, 512, 2, 4, 4, 768, 768, 768, 16, 2048, 6144, 2048,
                         2048, 2048, 8192, 2048, 1024, 4, 4, 4, 4, 4, 2};
    const float* srcs[23] = {w_f1, w_f2, w_scale, w_ru, w_rv, uw_in, uw_time, uw_mid, uw_out,
                             vw_patch, vw_qkv, vw_proj, vw_time, vw_text, vw_mlp1, vw_mlp2,
                             vw_unp, ca_wq, ca_wk, ca_wv, ca_wo, gw1, gw2};
    float* dsts[23] = {s_wf1, s_wf2, s_wsc, s_wru, s_wrv, s_uwin, s_uwt, s_uwm, s_uwo,
                       s_vwp, s_vwqkv, s_vwpr, s_vwti, s_vwte, s_vwm1, s_vwm2,
                       s_vwun, s_cawq, s_cawk, s_cawv, s_cawo, s_gw1, s_gw2};
    int fans[23] = {256, 1024, 512, 516, 516, 36, 512, 1728, 1728, 256, 512, 512,
                    512, 768, 512, 2048, 512, 4, 4, 4, 4, 8, 4};
    int cum = 0;
    for (int i = 0; i < 23; ++i) {
        tab.e[i].w = srcs[i]; tab.e[i].o = dsts[i];
        tab.e[i].fan = fans[i]; tab.e[i].rowStart = cum;
        cum += rowCounts[i];
    }
    rowscale_all_kernel<<<dim3(cum), dim3(256), 0, stream>>>(tab);
    wmid_cvt_kernel<<<dim3((1327104 + 255) / 256), dim3(256), 0, stream>>>(uw_mid, s_uwm, wtmid);

    auto gemv = [&](int ACT, int HASRES, const float* A, const float* W2, const float* wsc,
                    const float* res, float osc, float* o, int M, int N, int K) {
        dim3 g(M * N / 4);
        if (ACT)
            gemv_kernel<1, 0><<<g, 256, 0, stream>>>(A, W2, wsc, res, osc, o, N, K);
        else if (HASRES)
            gemv_kernel<0, 1><<<g, 256, 0, stream>>>(A, W2, wsc, res, osc, o, N, K);
        else
            gemv_kernel<0, 0><<<g, 256, 0, stream>>>(A, W2, wsc, res, osc, o, N, K);
    };

    // ---- time embedding chain
    femb_kernel<<<dim3(4), dim3(256), 0, stream>>>(time_vec, f_freq, f_phase, femb);
    gemv(1, 0, femb, w_f1, s_wf1, nullptr, 1.f, h1, 4, 1024, 256);
    gemv(0, 0, h1, w_f2, s_wf2, nullptr, 1.f, temb, 4, 512, 1024);

    scale_kernel<<<dim3(1), dim3(64), 0, stream>>>(temb, w_scale, s_wsc, zeta, scale2);
    meanx_kernel<<<dim3(16), dim3(256), 0, stream>>>(x, mean_x);
    router_kernel<<<dim3(1), dim3(64), 0, stream>>>(mean_x, scale2, temb, w_ru, s_wru, w_rv, s_wrv,
                                                    zeta, eidx, gain, rwv, out + 65536);
    make_inputs_kernel<<<dim3(256), dim3(256), 0, stream>>>(x, scale2, in_vit, in_unet);
    textp_kernel<<<dim3(12), dim3(256), 0, stream>>>(text_emb, textp);
    patchify_kernel<<<dim3(256), dim3(256), 0, stream>>>(in_vit, patchtok);

    // per-expert UNet time mod: tvec [4b][4e*192]
    gemv(0, 0, temb, uw_time, s_uwt, nullptr, 1.f, tvec, 4, 768, 512);

    hipMemsetAsync(out_unet, 0, 65536 * sizeof(float), stream);

    // ---- UNet conv chain, slot-compacted
    conv_in_kernel<<<dim3(16, 24, 8), dim3(256), 0, stream>>>(
        in_unet, uw_in, s_uwin, tvec, eidx, bufA);
    conv_mid_mfma<<<dim3(32, 3, 8), dim3(256), 0, stream>>>(
        bufA, wtmid, eidx, bufB);
    conv_out_kernel<<<dim3(16, 8, 8), dim3(256), 0, stream>>>(
        bufB, uw_out, s_uwo, eidx, gain, out_unet);

    // ---- ViT cond vectors: vcond [4b][4e*512]
    gemv(0, 0, temb, vw_time, s_vwti, nullptr, 1.f, vcond, 4, 2048, 512);
    gemv(0, 1, textp, vw_text, s_vwte, vcond, 1.f, vcond, 4, 2048, 768);

    auto mlin = [&](int ACT, const unsigned short* A, int aE, const float* W2, int wE2,
                    const float* wsc, int wscE, const float* pos, int posE,
                    const float* cond, int condRow, int condE,
                    const unsigned short* res, int resE, float osc,
                    const float* gate, unsigned short* o, int outE, int M, int N, int K) {
        dim3 g(N / 64, M / 64, 4);
        if (ACT)
            mfma_linear_kernel<1><<<g, 256, 0, stream>>>(A, aE, W2, wE2, wsc, wscE, pos, posE,
                                                         cond, condRow, condE, res, resE, osc,
                                                         gate, o, outE, M, N, K);
        else
            mfma_linear_kernel<0><<<g, 256, 0, stream>>>(A, aE, W2, wE2, wsc, wscE, pos, posE,
                                                         cond, condRow, condE, res, resE, osc,
                                                         gate, o, outE, M, N, K);
    };

    // ---- ViT expert stack (bf16 activations)
    mlin(0, patchtok, 0, vw_patch, 131072, s_vwp, 512, v_pos, 32768,
         vcond, 2048, 512, nullptr, 0, 1.f, rwv, vtok, 131072, 256, 512, 256);
    mlin(0, vtok, 131072, vw_qkv, 786432, s_vwqkv, 1536, nullptr, 0,
         nullptr, 0, 0, nullptr, 0, 1.f, rwv, vqkv, 393216, 256, 1536, 512);
    vit_attn_kernel<<<dim3(128), dim3(256), 0, stream>>>(vqkv, rwv, vao);
    mlin(0, vao, 131072, vw_proj, 262144, s_vwpr, 512, nullptr, 0,
         nullptr, 0, 0, vtok, 131072, 0.70710678f, rwv, vtok2, 131072, 256, 512, 512);
    mlin(1, vtok2, 131072, vw_mlp1, 1048576, s_vwm1, 2048, nullptr, 0,
         nullptr, 0, 0, nullptr, 0, 1.f, rwv, vhid, 524288, 256, 2048, 512);
    mlin(0, vhid, 524288, vw_mlp2, 1048576, s_vwm2, 512, nullptr, 0,
         nullptr, 0, 0, vtok2, 131072, 0.70710678f, rwv, vtok3, 131072, 256, 512, 2048);
    mlin(0, vtok3, 131072, vw_unp, 131072, s_vwun, 256, nullptr, 0,
         nullptr, 0, 0, nullptr, 0, 1.f, rwv, vout, 65536, 256, 256, 512);
    unpatch_scatter_kernel<<<dim3(256), dim3(256), 0, stream>>>(vout, rwv, out_vit);

    // ---- cross attention + fused tail
    ca_qkv_kernel<<<dim3(64), dim3(256), 0, stream>>>(out_unet, out_vit, ca_wq, s_cawq,
                                                      ca_wk, s_cawk, ca_wv, s_cawv, caq, cak, cav);
    ca_attn_kernel<<<dim3(256), dim3(1024), 0, stream>>>(caq, cak, cav, cao);
    ca_final_kernel<<<dim3(64), dim3(256), 0, stream>>>(cao, out_unet, ca_wo, s_cawo,
                                                        gw1, s_gw1, gw2, s_gw2, out);
}